// Round 4
// baseline (556.646 us; speedup 1.0000x reference)
//
#include <hip/hip_runtime.h>
#include <hip/hip_bf16.h>

#define B_    4
#define C_    128
#define HW_   16384
#define K_    1024
#define NEG_  (-10000000.0f)
#define SCALE_ 0.08838834764831845f   // 128^-0.5

using bf16 = __hip_bfloat16;
typedef __bf16 b8v __attribute__((ext_vector_type(8)));
typedef __bf16 b4v __attribute__((ext_vector_type(4)));
typedef __bf16 b2v __attribute__((ext_vector_type(2)));
typedef float  f4v __attribute__((ext_vector_type(4)));

__device__ __forceinline__ b8v ldb8(const void* p) { return *(const b8v*)p; }
__device__ __forceinline__ b4v ldb4(const void* p) { return *(const b4v*)p; }
__device__ __forceinline__ void storev(float* p, float v) { *p = v; }
__device__ __forceinline__ void storev(bf16* p, float v)  { *p = __float2bfloat16(v); }

// ---------------------------------------------------------------------------
// Weight prep: fold BN scale into rows, convert fp32 -> bf16.
// ---------------------------------------------------------------------------
__global__ __launch_bounds__(256) void wprep_kernel(
    const float* __restrict__ Wq1, const float* __restrict__ sq1,
    const float* __restrict__ Wq2, const float* __restrict__ sq2,
    const float* __restrict__ Wo,  const float* __restrict__ so,
    const float* __restrict__ Wb,  const float* __restrict__ sb,
    __bf16* __restrict__ Wq1p, __bf16* __restrict__ Wq2p,
    __bf16* __restrict__ Wop,  __bf16* __restrict__ Wbp)
{
    const int idx = blockIdx.x * 256 + threadIdx.x;
    if (idx < 16384)      { Wq1p[idx] = (__bf16)(Wq1[idx] * sq1[idx >> 7]); }
    else if (idx < 32768) { const int i = idx - 16384; Wq2p[i] = (__bf16)(Wq2[i] * sq2[i >> 7]); }
    else if (idx < 49152) { const int i = idx - 32768; Wop[i]  = (__bf16)(Wo[i]  * so[i >> 7]); }
    else                  { const int i = idx - 49152; Wbp[i]  = (__bf16)(Wb[i]  * sb[i >> 8]); }
}

// ---------------------------------------------------------------------------
// Transpose query [b][c][p] fp32 -> qt [b][p][c] bf16. grid (HW/64, B).
// ---------------------------------------------------------------------------
__global__ __launch_bounds__(256) void tq_kernel(const float* __restrict__ query,
                                                 bf16* __restrict__ qt)
{
    __shared__ float Xs[64 * 129];
    const int p0 = blockIdx.x * 64, b = blockIdx.y, t = threadIdx.x;
    const int pl = t & 63, cg = t >> 6;
#pragma unroll 4
    for (int i = 0; i < 32; ++i) {
        const int c = cg * 32 + i;
        Xs[pl * 129 + c] = query[(size_t)(b * 128 + c) * HW_ + p0 + pl];
    }
    __syncthreads();
#pragma unroll 4
    for (int it = 0; it < 16; ++it) {
        const int p = it * 4 + cg;
        b2v pk;
        pk[0] = (__bf16)Xs[p * 129 + 2 * pl];
        pk[1] = (__bf16)Xs[p * 129 + 2 * pl + 1];
        *(b2v*)(qt + ((size_t)b * HW_ + p0 + p) * 128 + 2 * pl) = pk;
    }
}

// ---------------------------------------------------------------------------
// kv_proj: k (2 layers) -> kbuf [b][k][c] bf16 ; v (1 layer) -> vbuf [b][c][k].
// ---------------------------------------------------------------------------
__device__ __forceinline__ void layer128_lds(const float* __restrict__ Xs, float* __restrict__ Ysh,
                                             const float* __restrict__ W,
                                             const float* __restrict__ sc, const float* __restrict__ sh)
{
    const int t = threadIdx.x;
    const int o = t & 127;
    const int half = t >> 7;
    float acc[16];
#pragma unroll
    for (int p = 0; p < 16; ++p) acc[p] = 0.f;
    const float* wrow  = W + o * 128;
    const float* xbase = Xs + half * 16;
    for (int c = 0; c < 128; c += 4) {
        const float4 w4 = *(const float4*)(wrow + c);
        const float wj[4] = {w4.x, w4.y, w4.z, w4.w};
#pragma unroll
        for (int j = 0; j < 4; ++j) {
            const float* xr = xbase + (c + j) * 33;
#pragma unroll
            for (int p = 0; p < 16; ++p) acc[p] += wj[j] * xr[p];
        }
    }
    const float s = sc[o], h = sh[o];
    float* yb = Ysh + o * 33 + half * 16;
#pragma unroll
    for (int p = 0; p < 16; ++p) yb[p] = fmaxf(fmaf(s, acc[p], h), 0.f);
}

template <typename OutT>
__device__ __forceinline__ void layer128_store(const float* __restrict__ Xs, OutT* __restrict__ outp,
                                               const float* __restrict__ W,
                                               const float* __restrict__ sc, const float* __restrict__ sh)
{
    const int t = threadIdx.x;
    const int o = t & 127;
    const int half = t >> 7;
    float acc[16];
#pragma unroll
    for (int p = 0; p < 16; ++p) acc[p] = 0.f;
    const float* wrow  = W + o * 128;
    const float* xbase = Xs + half * 16;
    for (int c = 0; c < 128; c += 4) {
        const float4 w4 = *(const float4*)(wrow + c);
        const float wj[4] = {w4.x, w4.y, w4.z, w4.w};
#pragma unroll
        for (int j = 0; j < 4; ++j) {
            const float* xr = xbase + (c + j) * 33;
#pragma unroll
            for (int p = 0; p < 16; ++p) acc[p] += wj[j] * xr[p];
        }
    }
    const float s = sc[o], h = sh[o];
#pragma unroll
    for (int p = 0; p < 16; ++p) {
        float v = fmaxf(fmaf(s, acc[p], h), 0.f);
        storev(&outp[(size_t)(half * 16 + p) * 128 + o], v);
    }
}

__global__ __launch_bounds__(256) void kv_proj_kernel(
    const float* __restrict__ key, const float* __restrict__ val,
    const float* __restrict__ Wk1, const float* __restrict__ sk1, const float* __restrict__ bk1,
    const float* __restrict__ Wk2, const float* __restrict__ sk2, const float* __restrict__ bk2,
    const float* __restrict__ Wv,  const float* __restrict__ sv,  const float* __restrict__ bv,
    bf16* __restrict__ kbuf, bf16* __restrict__ vbuf)
{
    __shared__ __align__(16) float X[128 * 33];
    __shared__ __align__(16) float Y[128 * 33];
    const int p0 = blockIdx.x * 32;
    const int b  = blockIdx.y;
    const int t  = threadIdx.x;

    for (int e = t; e < 4096; e += 256) {
        int c = e >> 5, p = e & 31;
        X[c * 33 + p] = key[(size_t)(b * 128 + c) * K_ + p0 + p];
    }
    __syncthreads();
    layer128_lds(X, Y, Wk1, sk1, bk1);
    __syncthreads();
    layer128_store(Y, kbuf + (size_t)(b * K_ + p0) * 128, Wk2, sk2, bk2);
    __syncthreads();
    for (int e = t; e < 4096; e += 256) {
        int c = e >> 5, p = e & 31;
        X[c * 33 + p] = val[(size_t)(b * 128 + c) * K_ + p0 + p];
    }
    __syncthreads();
    layer128_lds(X, Y, Wv, sv, bv);
    __syncthreads();
    for (int e = t; e < 4096; e += 256) {
        int c = e >> 5, p = e & 31;
        vbuf[(size_t)(b * 128 + c) * K_ + p0 + p] = __float2bfloat16(Y[c * 33 + p]);
    }
}

// ---------------------------------------------------------------------------
// q projection via MFMA (unchanged from R3). grid (HW/128, B).
// ---------------------------------------------------------------------------
__global__ __launch_bounds__(256, 2) void qproj_kernel(
    const bf16* __restrict__ qt,
    const __bf16* __restrict__ W1, const float* __restrict__ sh1,
    const __bf16* __restrict__ W2, const float* __restrict__ sh2,
    bf16* __restrict__ qbuf)
{
    __shared__ __bf16 Ys[128 * 136];
    const int t = threadIdx.x, w = t >> 6, lane = t & 63;
    const int pl = lane & 15, quad = lane >> 4;
    const int n0 = blockIdx.x * 128, b = blockIdx.y;
    const int ob = 32 * w;

    b8v W1f[2][4], W2f[2][4];
#pragma unroll
    for (int mt = 0; mt < 2; ++mt)
#pragma unroll
        for (int s = 0; s < 4; ++s) {
            W1f[mt][s] = ldb8(W1 + (ob + mt * 16 + pl) * 128 + s * 32 + quad * 8);
            W2f[mt][s] = ldb8(W2 + (ob + mt * 16 + pl) * 128 + s * 32 + quad * 8);
        }

    const bf16* qtb = qt + ((size_t)b * HW_ + n0) * 128;

    f4v acc[2][8];
#pragma unroll
    for (int mt = 0; mt < 2; ++mt)
#pragma unroll
        for (int nt = 0; nt < 8; ++nt) acc[mt][nt] = (f4v){0.f, 0.f, 0.f, 0.f};

#pragma unroll
    for (int s = 0; s < 4; ++s) {
        b8v Bf[8];
#pragma unroll
        for (int nt = 0; nt < 8; ++nt)
            Bf[nt] = ldb8(qtb + (size_t)(nt * 16 + pl) * 128 + s * 32 + quad * 8);
#pragma unroll
        for (int mt = 0; mt < 2; ++mt)
#pragma unroll
            for (int nt = 0; nt < 8; ++nt)
                acc[mt][nt] = __builtin_amdgcn_mfma_f32_16x16x32_bf16(W1f[mt][s], Bf[nt], acc[mt][nt], 0, 0, 0);
    }

#pragma unroll
    for (int mt = 0; mt < 2; ++mt) {
        const float4 s4 = *(const float4*)(sh1 + ob + mt * 16 + quad * 4);
        const float shf[4] = {s4.x, s4.y, s4.z, s4.w};
#pragma unroll
        for (int nt = 0; nt < 8; ++nt) {
            b4v y;
#pragma unroll
            for (int r = 0; r < 4; ++r) y[r] = (__bf16)fmaxf(acc[mt][nt][r] + shf[r], 0.f);
            *(b4v*)&Ys[(nt * 16 + pl) * 136 + ob + mt * 16 + quad * 4] = y;
        }
    }
    __syncthreads();

    f4v acc2[2][8];
#pragma unroll
    for (int mt = 0; mt < 2; ++mt)
#pragma unroll
        for (int nt = 0; nt < 8; ++nt) acc2[mt][nt] = (f4v){0.f, 0.f, 0.f, 0.f};

#pragma unroll
    for (int s = 0; s < 4; ++s) {
        b8v Bf[8];
#pragma unroll
        for (int nt = 0; nt < 8; ++nt)
            Bf[nt] = *(const b8v*)&Ys[(nt * 16 + pl) * 136 + s * 32 + quad * 8];
#pragma unroll
        for (int mt = 0; mt < 2; ++mt)
#pragma unroll
            for (int nt = 0; nt < 8; ++nt)
                acc2[mt][nt] = __builtin_amdgcn_mfma_f32_16x16x32_bf16(W2f[mt][s], Bf[nt], acc2[mt][nt], 0, 0, 0);
    }

    bf16* qb = qbuf + ((size_t)b * HW_ + n0) * 128;
#pragma unroll
    for (int mt = 0; mt < 2; ++mt) {
        const float4 s4 = *(const float4*)(sh2 + ob + mt * 16 + quad * 4);
        const float shf[4] = {s4.x, s4.y, s4.z, s4.w};
#pragma unroll
        for (int nt = 0; nt < 8; ++nt) {
            b4v y;
#pragma unroll
            for (int r = 0; r < 4; ++r) y[r] = (__bf16)fmaxf(acc2[mt][nt][r] + shf[r], 0.f);
            *(b4v*)(qb + (size_t)(nt * 16 + pl) * 128 + ob + mt * 16 + quad * 4) = y;
        }
    }
}

// ---------------------------------------------------------------------------
// Kernel 3: flash attention, transposed-sim register pipeline.
//   GEMM1: simT = k @ q^T  (A=k rows -> M=key, B=q rows -> N=query)
//          D layout: lane holds keys quad*4+r (+16*kt), query = lane&15.
//   Softmax: per-query stats are in-lane over 16 values + shfl_xor(16,32).
//   GEMM2: ctx = P @ v. A-frag = packed P registers directly (key order inside
//          the K=32 step is permuted; v B-frags load the same permuted keys:
//          slot j<4 -> k0+s*32+quad*4+j, j>=4 -> k0+s*32+16+quad*4+(j-4)).
// No LDS for P, no barriers in the K-loop. grid (HW/64, B), 256 threads.
// ---------------------------------------------------------------------------
__global__ __launch_bounds__(256) void attn_kernel(
    const bf16* __restrict__ qbuf, const bf16* __restrict__ kbuf, const bf16* __restrict__ vbuf,
    const int* __restrict__ mask, bf16* __restrict__ ctxbuf)
{
    __shared__ __align__(16) float bias[K_];

    const int t    = threadIdx.x;
    const int w    = t >> 6;
    const int lane = t & 63;
    const int m    = lane & 15;
    const int quad = lane >> 4;
    const int q0   = blockIdx.x * 64;
    const int b    = blockIdx.y;

    for (int i = t; i < K_; i += 256)
        bias[i] = (mask[b * K_ + i] != 0) ? 0.f : NEG_;
    __syncthreads();

    // B-frags of q: lane m -> query q0+w*16+m, 4 K-steps of 32 channels
    b8v qf[4];
    {
        const bf16* qrow = qbuf + ((size_t)b * HW_ + q0 + w * 16 + m) * 128;
#pragma unroll
        for (int s = 0; s < 4; ++s) qf[s] = ldb8(qrow + s * 32 + quad * 8);
    }

    const bf16* kb = kbuf + (size_t)b * K_ * 128;
    const bf16* vb = vbuf + (size_t)b * 128 * K_;

    f4v acc[8];
#pragma unroll
    for (int i = 0; i < 8; ++i) acc[i] = (f4v){0.f, 0.f, 0.f, 0.f};
    float mrun = -3.0e38f, lrun = 0.f;

    for (int chunk = 0; chunk < 16; ++chunk) {
        const int k0 = chunk * 64;

        // ---- GEMM1: simT tiles. sv[kt][r] = sim[key=k0+kt*16+quad*4+r][q=m]
        f4v sv[4];
#pragma unroll
        for (int kt = 0; kt < 4; ++kt) {
            f4v a = (f4v){0.f, 0.f, 0.f, 0.f};
            const bf16* krow = kb + (size_t)(k0 + kt * 16 + m) * 128 + quad * 8;
#pragma unroll
            for (int s = 0; s < 4; ++s)
                a = __builtin_amdgcn_mfma_f32_16x16x32_bf16(ldb8(krow + s * 32), qf[s], a, 0, 0, 0);
            const float4 b4 = *(const float4*)&bias[k0 + kt * 16 + quad * 4];
            const float bb4[4] = {b4.x, b4.y, b4.z, b4.w};
#pragma unroll
            for (int r = 0; r < 4; ++r) sv[kt][r] = a[r] * SCALE_ + bb4[r];
        }

        // ---- online softmax (all 16 values in lane share q = m)
        float mloc = sv[0][0];
#pragma unroll
        for (int kt = 0; kt < 4; ++kt)
#pragma unroll
            for (int r = 0; r < 4; ++r) mloc = fmaxf(mloc, sv[kt][r]);
        mloc = fmaxf(mloc, __shfl_xor(mloc, 16, 64));
        mloc = fmaxf(mloc, __shfl_xor(mloc, 32, 64));
        const float mn = fmaxf(mrun, mloc);
        const float alpha = __expf(mrun - mn);
        mrun = mn;

        b4v pk[4];
        float rs = 0.f;
#pragma unroll
        for (int kt = 0; kt < 4; ++kt)
#pragma unroll
            for (int r = 0; r < 4; ++r) {
                const float p = __expf(sv[kt][r] - mn);
                rs += p;
                pk[kt][r] = (__bf16)p;
            }
        rs += __shfl_xor(rs, 16, 64);
        rs += __shfl_xor(rs, 32, 64);
        lrun = lrun * alpha + rs;

        // broadcast alpha for accumulator rows q = quad*4+r
        float alr[4];
#pragma unroll
        for (int r = 0; r < 4; ++r) alr[r] = __shfl(alpha, quad * 4 + r, 64);
#pragma unroll
        for (int ct = 0; ct < 8; ++ct)
#pragma unroll
            for (int r = 0; r < 4; ++r) acc[ct][r] *= alr[r];

        // ---- GEMM2: ctx += P @ v (A = packed P regs, permuted key order)
        const b8v A0 = __builtin_shufflevector(pk[0], pk[1], 0, 1, 2, 3, 4, 5, 6, 7);
        const b8v A1 = __builtin_shufflevector(pk[2], pk[3], 0, 1, 2, 3, 4, 5, 6, 7);
#pragma unroll
        for (int ct = 0; ct < 8; ++ct) {
            const bf16* vrow = vb + (size_t)(ct * 16 + m) * K_ + k0;
            const b8v B0 = __builtin_shufflevector(ldb4(vrow + quad * 4),      ldb4(vrow + 16 + quad * 4), 0, 1, 2, 3, 4, 5, 6, 7);
            const b8v B1 = __builtin_shufflevector(ldb4(vrow + 32 + quad * 4), ldb4(vrow + 48 + quad * 4), 0, 1, 2, 3, 4, 5, 6, 7);
            acc[ct] = __builtin_amdgcn_mfma_f32_16x16x32_bf16(A0, B0, acc[ct], 0, 0, 0);
            acc[ct] = __builtin_amdgcn_mfma_f32_16x16x32_bf16(A1, B1, acc[ct], 0, 0, 0);
        }
    }

    // ---- epilogue: acc row q = quad*4+r, col c = ct*16+m
    float inv[4];
#pragma unroll
    for (int r = 0; r < 4; ++r) inv[r] = 1.f / __shfl(lrun, quad * 4 + r, 64);
    bf16* crow = ctxbuf + ((size_t)b * HW_ + q0 + w * 16) * 128;
#pragma unroll
    for (int ct = 0; ct < 8; ++ct)
#pragma unroll
        for (int r = 0; r < 4; ++r)
            crow[(size_t)(quad * 4 + r) * 128 + ct * 16 + m] = __float2bfloat16(acc[ct][r] * inv[r]);
}

// ---------------------------------------------------------------------------
// Final: ctx2 = relu(Wo'@ctx + bo); out = relu(Wb'@[ctx2;qt] + bb) via MFMA.
// ---------------------------------------------------------------------------
__global__ __launch_bounds__(256, 2) void final_kernel(
    const bf16* __restrict__ ctx, const bf16* __restrict__ qt,
    const __bf16* __restrict__ Wop, const float* __restrict__ bo,
    const __bf16* __restrict__ Wbp, const float* __restrict__ bb,
    float* __restrict__ out)
{
    __shared__ __bf16 Ys[128 * 136];
    const int t = threadIdx.x, w = t >> 6, lane = t & 63;
    const int pl = lane & 15, quad = lane >> 4;
    const int n0 = blockIdx.x * 128, b = blockIdx.y;
    const int ob = 32 * w;

    b8v Wof[2][4];
#pragma unroll
    for (int mt = 0; mt < 2; ++mt)
#pragma unroll
        for (int s = 0; s < 4; ++s)
            Wof[mt][s] = ldb8(Wop + (ob + mt * 16 + pl) * 128 + s * 32 + quad * 8);

    const bf16* cb = ctx + ((size_t)b * HW_ + n0) * 128;

    f4v acc1[2][8];
#pragma unroll
    for (int mt = 0; mt < 2; ++mt)
#pragma unroll
        for (int nt = 0; nt < 8; ++nt) acc1[mt][nt] = (f4v){0.f, 0.f, 0.f, 0.f};

#pragma unroll
    for (int s = 0; s < 4; ++s) {
        b8v Bf[8];
#pragma unroll
        for (int nt = 0; nt < 8; ++nt)
            Bf[nt] = ldb8(cb + (size_t)(nt * 16 + pl) * 128 + s * 32 + quad * 8);
#pragma unroll
        for (int mt = 0; mt < 2; ++mt)
#pragma unroll
            for (int nt = 0; nt < 8; ++nt)
                acc1[mt][nt] = __builtin_amdgcn_mfma_f32_16x16x32_bf16(Wof[mt][s], Bf[nt], acc1[mt][nt], 0, 0, 0);
    }

#pragma unroll
    for (int mt = 0; mt < 2; ++mt) {
        const float4 s4 = *(const float4*)(bo + ob + mt * 16 + quad * 4);
        const float shf[4] = {s4.x, s4.y, s4.z, s4.w};
#pragma unroll
        for (int nt = 0; nt < 8; ++nt) {
            b4v y;
#pragma unroll
            for (int r = 0; r < 4; ++r) y[r] = (__bf16)fmaxf(acc1[mt][nt][r] + shf[r], 0.f);
            *(b4v*)&Ys[(nt * 16 + pl) * 136 + ob + mt * 16 + quad * 4] = y;
        }
    }
    __syncthreads();

    const bf16* qtb = qt + ((size_t)b * HW_ + n0) * 128;
    f4v acc2[4][8];
#pragma unroll
    for (int mt = 0; mt < 4; ++mt)
#pragma unroll
        for (int nt = 0; nt < 8; ++nt) acc2[mt][nt] = (f4v){0.f, 0.f, 0.f, 0.f};

#pragma unroll
    for (int ks = 0; ks < 8; ++ks) {
        b8v Af[4];
#pragma unroll
        for (int mt = 0; mt < 4; ++mt)
            Af[mt] = ldb8(Wbp + (64 * w + mt * 16 + pl) * 256 + ks * 32 + quad * 8);
        b8v Bf[8];
        if (ks < 4) {
#pragma unroll
            for (int nt = 0; nt < 8; ++nt)
                Bf[nt] = *(const b8v*)&Ys[(nt * 16 + pl) * 136 + ks * 32 + quad * 8];
        } else {
#pragma unroll
            for (int nt = 0; nt < 8; ++nt)
                Bf[nt] = ldb8(qtb + (size_t)(nt * 16 + pl) * 128 + (ks - 4) * 32 + quad * 8);
        }
#pragma unroll
        for (int mt = 0; mt < 4; ++mt)
#pragma unroll
            for (int nt = 0; nt < 8; ++nt)
                acc2[mt][nt] = __builtin_amdgcn_mfma_f32_16x16x32_bf16(Af[mt], Bf[nt], acc2[mt][nt], 0, 0, 0);
    }

#pragma unroll
    for (int mt = 0; mt < 4; ++mt) {
        const float4 s4 = *(const float4*)(bb + 64 * w + mt * 16 + quad * 4);
        const float shf[4] = {s4.x, s4.y, s4.z, s4.w};
#pragma unroll
        for (int nt = 0; nt < 8; ++nt)
#pragma unroll
            for (int r = 0; r < 4; ++r)
                out[(size_t)(b * 256 + 64 * w + mt * 16 + quad * 4 + r) * HW_ + n0 + nt * 16 + pl]
                    = fmaxf(acc2[mt][nt][r] + shf[r], 0.f);
    }
}

// ---------------------------------------------------------------------------
extern "C" void kernel_launch(void* const* d_in, const int* in_sizes, int n_in,
                              void* d_out, int out_size, void* d_ws, size_t ws_size,
                              hipStream_t stream)
{
    const float* query = (const float*)d_in[0];
    const float* key   = (const float*)d_in[1];
    const float* val   = (const float*)d_in[2];
    const int*   mask  = (const int*)  d_in[3];
    const float* Wq1 = (const float*)d_in[4];  const float* sq1 = (const float*)d_in[5];  const float* bq1 = (const float*)d_in[6];
    const float* Wq2 = (const float*)d_in[7];  const float* sq2 = (const float*)d_in[8];  const float* bq2 = (const float*)d_in[9];
    const float* Wk1 = (const float*)d_in[10]; const float* sk1 = (const float*)d_in[11]; const float* bk1 = (const float*)d_in[12];
    const float* Wk2 = (const float*)d_in[13]; const float* sk2 = (const float*)d_in[14]; const float* bk2 = (const float*)d_in[15];
    const float* Wv  = (const float*)d_in[16]; const float* sv  = (const float*)d_in[17]; const float* bv  = (const float*)d_in[18];
    const float* Wo  = (const float*)d_in[19]; const float* so  = (const float*)d_in[20]; const float* bo  = (const float*)d_in[21];
    const float* Wb  = (const float*)d_in[22]; const float* sb  = (const float*)d_in[23]; const float* bb  = (const float*)d_in[24];

    char* ws = (char*)d_ws;
    bf16*   kbuf = (bf16*)(ws);                        // [B][K][C] bf16  : 1 MB
    bf16*   vbuf = (bf16*)(ws + (1u << 20));           // [B][C][K] bf16  : 1 MB
    bf16*   qbuf = (bf16*)(ws + (2u << 20));           // [B][HW][C] bf16 : 16 MB
    bf16*   ctxb = (bf16*)(ws + (18u << 20));          // [B][HW][C] bf16 : 16 MB
    bf16*   qt   = (bf16*)(ws + (34u << 20));          // [B][HW][C] bf16 : 16 MB
    __bf16* Wq1p = (__bf16*)(ws + (50u << 20));                  // 32 KB
    __bf16* Wq2p = (__bf16*)(ws + (50u << 20) + (32u << 10));    // 32 KB
    __bf16* Wop  = (__bf16*)(ws + (50u << 20) + (64u << 10));    // 32 KB
    __bf16* Wbp  = (__bf16*)(ws + (50u << 20) + (96u << 10));    // 128 KB
    float* outp = (float*)d_out;

    wprep_kernel<<<448, 256, 0, stream>>>(Wq1, sq1, Wq2, sq2, Wo, so, Wb, sb,
                                          Wq1p, Wq2p, Wop, Wbp);
    tq_kernel<<<dim3(HW_ / 64, B_), 256, 0, stream>>>(query, qt);
    kv_proj_kernel<<<dim3(K_ / 32, B_), 256, 0, stream>>>(
        key, val, Wk1, sk1, bk1, Wk2, sk2, bk2, Wv, sv, bv, kbuf, vbuf);
    qproj_kernel<<<dim3(HW_ / 128, B_), 256, 0, stream>>>(
        qt, Wq1p, bq1, Wq2p, bq2, qbuf);
    attn_kernel<<<dim3(HW_ / 64, B_), 256, 0, stream>>>(
        qbuf, kbuf, vbuf, mask, ctxb);
    final_kernel<<<dim3(HW_ / 128, B_), 256, 0, stream>>>(
        ctxb, qt, Wop, bo, Wbp, bb, outp);
}

// Round 5
// 410.566 us; speedup vs baseline: 1.3558x; 1.3558x over previous
//
#include <hip/hip_runtime.h>
#include <hip/hip_bf16.h>

#define B_    4
#define C_    128
#define HW_   16384
#define K_    1024
#define NEG_  (-10000000.0f)
#define SCALE_ 0.08838834764831845f   // 128^-0.5

using bf16 = __hip_bfloat16;
typedef __bf16 b8v __attribute__((ext_vector_type(8)));
typedef __bf16 b4v __attribute__((ext_vector_type(4)));
typedef __bf16 b2v __attribute__((ext_vector_type(2)));
typedef float  f4v __attribute__((ext_vector_type(4)));

__device__ __forceinline__ b8v ldb8(const void* p) { return *(const b8v*)p; }
__device__ __forceinline__ b4v ldb4(const void* p) { return *(const b4v*)p; }
__device__ __forceinline__ void storev(float* p, float v) { *p = v; }
__device__ __forceinline__ void storev(bf16* p, float v)  { *p = __float2bfloat16(v); }

// ---------------------------------------------------------------------------
// Weight prep: fold BN scale into rows, convert fp32 -> bf16.
// ---------------------------------------------------------------------------
__global__ __launch_bounds__(256) void wprep_kernel(
    const float* __restrict__ Wq1, const float* __restrict__ sq1,
    const float* __restrict__ Wq2, const float* __restrict__ sq2,
    const float* __restrict__ Wo,  const float* __restrict__ so,
    const float* __restrict__ Wb,  const float* __restrict__ sb,
    __bf16* __restrict__ Wq1p, __bf16* __restrict__ Wq2p,
    __bf16* __restrict__ Wop,  __bf16* __restrict__ Wbp)
{
    const int idx = blockIdx.x * 256 + threadIdx.x;
    if (idx < 16384)      { Wq1p[idx] = (__bf16)(Wq1[idx] * sq1[idx >> 7]); }
    else if (idx < 32768) { const int i = idx - 16384; Wq2p[i] = (__bf16)(Wq2[i] * sq2[i >> 7]); }
    else if (idx < 49152) { const int i = idx - 32768; Wop[i]  = (__bf16)(Wo[i]  * so[i >> 7]); }
    else                  { const int i = idx - 49152; Wbp[i]  = (__bf16)(Wb[i]  * sb[i >> 8]); }
}

// ---------------------------------------------------------------------------
// Transpose query [b][c][p] fp32 -> qt [b][p][c] bf16. grid (HW/64, B).
// ---------------------------------------------------------------------------
__global__ __launch_bounds__(256) void tq_kernel(const float* __restrict__ query,
                                                 bf16* __restrict__ qt)
{
    __shared__ float Xs[64 * 129];
    const int p0 = blockIdx.x * 64, b = blockIdx.y, t = threadIdx.x;
    const int pl = t & 63, cg = t >> 6;
#pragma unroll 4
    for (int i = 0; i < 32; ++i) {
        const int c = cg * 32 + i;
        Xs[pl * 129 + c] = query[(size_t)(b * 128 + c) * HW_ + p0 + pl];
    }
    __syncthreads();
#pragma unroll 4
    for (int it = 0; it < 16; ++it) {
        const int p = it * 4 + cg;
        b2v pk;
        pk[0] = (__bf16)Xs[p * 129 + 2 * pl];
        pk[1] = (__bf16)Xs[p * 129 + 2 * pl + 1];
        *(b2v*)(qt + ((size_t)b * HW_ + p0 + p) * 128 + 2 * pl) = pk;
    }
}

// ---------------------------------------------------------------------------
// kv_proj: k (2 layers) -> kbuf [b][k][c] bf16 ; v (1 layer) -> vbuf [b][c][k].
// ---------------------------------------------------------------------------
__device__ __forceinline__ void layer128_lds(const float* __restrict__ Xs, float* __restrict__ Ysh,
                                             const float* __restrict__ W,
                                             const float* __restrict__ sc, const float* __restrict__ sh)
{
    const int t = threadIdx.x;
    const int o = t & 127;
    const int half = t >> 7;
    float acc[16];
#pragma unroll
    for (int p = 0; p < 16; ++p) acc[p] = 0.f;
    const float* wrow  = W + o * 128;
    const float* xbase = Xs + half * 16;
    for (int c = 0; c < 128; c += 4) {
        const float4 w4 = *(const float4*)(wrow + c);
        const float wj[4] = {w4.x, w4.y, w4.z, w4.w};
#pragma unroll
        for (int j = 0; j < 4; ++j) {
            const float* xr = xbase + (c + j) * 33;
#pragma unroll
            for (int p = 0; p < 16; ++p) acc[p] += wj[j] * xr[p];
        }
    }
    const float s = sc[o], h = sh[o];
    float* yb = Ysh + o * 33 + half * 16;
#pragma unroll
    for (int p = 0; p < 16; ++p) yb[p] = fmaxf(fmaf(s, acc[p], h), 0.f);
}

template <typename OutT>
__device__ __forceinline__ void layer128_store(const float* __restrict__ Xs, OutT* __restrict__ outp,
                                               const float* __restrict__ W,
                                               const float* __restrict__ sc, const float* __restrict__ sh)
{
    const int t = threadIdx.x;
    const int o = t & 127;
    const int half = t >> 7;
    float acc[16];
#pragma unroll
    for (int p = 0; p < 16; ++p) acc[p] = 0.f;
    const float* wrow  = W + o * 128;
    const float* xbase = Xs + half * 16;
    for (int c = 0; c < 128; c += 4) {
        const float4 w4 = *(const float4*)(wrow + c);
        const float wj[4] = {w4.x, w4.y, w4.z, w4.w};
#pragma unroll
        for (int j = 0; j < 4; ++j) {
            const float* xr = xbase + (c + j) * 33;
#pragma unroll
            for (int p = 0; p < 16; ++p) acc[p] += wj[j] * xr[p];
        }
    }
    const float s = sc[o], h = sh[o];
#pragma unroll
    for (int p = 0; p < 16; ++p) {
        float v = fmaxf(fmaf(s, acc[p], h), 0.f);
        storev(&outp[(size_t)(half * 16 + p) * 128 + o], v);
    }
}

__global__ __launch_bounds__(256) void kv_proj_kernel(
    const float* __restrict__ key, const float* __restrict__ val,
    const float* __restrict__ Wk1, const float* __restrict__ sk1, const float* __restrict__ bk1,
    const float* __restrict__ Wk2, const float* __restrict__ sk2, const float* __restrict__ bk2,
    const float* __restrict__ Wv,  const float* __restrict__ sv,  const float* __restrict__ bv,
    bf16* __restrict__ kbuf, bf16* __restrict__ vbuf)
{
    __shared__ __align__(16) float X[128 * 33];
    __shared__ __align__(16) float Y[128 * 33];
    const int p0 = blockIdx.x * 32;
    const int b  = blockIdx.y;
    const int t  = threadIdx.x;

    for (int e = t; e < 4096; e += 256) {
        int c = e >> 5, p = e & 31;
        X[c * 33 + p] = key[(size_t)(b * 128 + c) * K_ + p0 + p];
    }
    __syncthreads();
    layer128_lds(X, Y, Wk1, sk1, bk1);
    __syncthreads();
    layer128_store(Y, kbuf + (size_t)(b * K_ + p0) * 128, Wk2, sk2, bk2);
    __syncthreads();
    for (int e = t; e < 4096; e += 256) {
        int c = e >> 5, p = e & 31;
        X[c * 33 + p] = val[(size_t)(b * 128 + c) * K_ + p0 + p];
    }
    __syncthreads();
    layer128_lds(X, Y, Wv, sv, bv);
    __syncthreads();
    for (int e = t; e < 4096; e += 256) {
        int c = e >> 5, p = e & 31;
        vbuf[(size_t)(b * 128 + c) * K_ + p0 + p] = __float2bfloat16(Y[c * 33 + p]);
    }
}

// ---------------------------------------------------------------------------
// q projection via MFMA (unchanged). grid (HW/128, B).
// ---------------------------------------------------------------------------
__global__ __launch_bounds__(256, 2) void qproj_kernel(
    const bf16* __restrict__ qt,
    const __bf16* __restrict__ W1, const float* __restrict__ sh1,
    const __bf16* __restrict__ W2, const float* __restrict__ sh2,
    bf16* __restrict__ qbuf)
{
    __shared__ __bf16 Ys[128 * 136];
    const int t = threadIdx.x, w = t >> 6, lane = t & 63;
    const int pl = lane & 15, quad = lane >> 4;
    const int n0 = blockIdx.x * 128, b = blockIdx.y;
    const int ob = 32 * w;

    b8v W1f[2][4], W2f[2][4];
#pragma unroll
    for (int mt = 0; mt < 2; ++mt)
#pragma unroll
        for (int s = 0; s < 4; ++s) {
            W1f[mt][s] = ldb8(W1 + (ob + mt * 16 + pl) * 128 + s * 32 + quad * 8);
            W2f[mt][s] = ldb8(W2 + (ob + mt * 16 + pl) * 128 + s * 32 + quad * 8);
        }

    const bf16* qtb = qt + ((size_t)b * HW_ + n0) * 128;

    f4v acc[2][8];
#pragma unroll
    for (int mt = 0; mt < 2; ++mt)
#pragma unroll
        for (int nt = 0; nt < 8; ++nt) acc[mt][nt] = (f4v){0.f, 0.f, 0.f, 0.f};

#pragma unroll
    for (int s = 0; s < 4; ++s) {
        b8v Bf[8];
#pragma unroll
        for (int nt = 0; nt < 8; ++nt)
            Bf[nt] = ldb8(qtb + (size_t)(nt * 16 + pl) * 128 + s * 32 + quad * 8);
#pragma unroll
        for (int mt = 0; mt < 2; ++mt)
#pragma unroll
            for (int nt = 0; nt < 8; ++nt)
                acc[mt][nt] = __builtin_amdgcn_mfma_f32_16x16x32_bf16(W1f[mt][s], Bf[nt], acc[mt][nt], 0, 0, 0);
    }

#pragma unroll
    for (int mt = 0; mt < 2; ++mt) {
        const float4 s4 = *(const float4*)(sh1 + ob + mt * 16 + quad * 4);
        const float shf[4] = {s4.x, s4.y, s4.z, s4.w};
#pragma unroll
        for (int nt = 0; nt < 8; ++nt) {
            b4v y;
#pragma unroll
            for (int r = 0; r < 4; ++r) y[r] = (__bf16)fmaxf(acc[mt][nt][r] + shf[r], 0.f);
            *(b4v*)&Ys[(nt * 16 + pl) * 136 + ob + mt * 16 + quad * 4] = y;
        }
    }
    __syncthreads();

    f4v acc2[2][8];
#pragma unroll
    for (int mt = 0; mt < 2; ++mt)
#pragma unroll
        for (int nt = 0; nt < 8; ++nt) acc2[mt][nt] = (f4v){0.f, 0.f, 0.f, 0.f};

#pragma unroll
    for (int s = 0; s < 4; ++s) {
        b8v Bf[8];
#pragma unroll
        for (int nt = 0; nt < 8; ++nt)
            Bf[nt] = *(const b8v*)&Ys[(nt * 16 + pl) * 136 + s * 32 + quad * 8];
#pragma unroll
        for (int mt = 0; mt < 2; ++mt)
#pragma unroll
            for (int nt = 0; nt < 8; ++nt)
                acc2[mt][nt] = __builtin_amdgcn_mfma_f32_16x16x32_bf16(W2f[mt][s], Bf[nt], acc2[mt][nt], 0, 0, 0);
    }

    bf16* qb = qbuf + ((size_t)b * HW_ + n0) * 128;
#pragma unroll
    for (int mt = 0; mt < 2; ++mt) {
        const float4 s4 = *(const float4*)(sh2 + ob + mt * 16 + quad * 4);
        const float shf[4] = {s4.x, s4.y, s4.z, s4.w};
#pragma unroll
        for (int nt = 0; nt < 8; ++nt) {
            b4v y;
#pragma unroll
            for (int r = 0; r < 4; ++r) y[r] = (__bf16)fmaxf(acc2[mt][nt][r] + shf[r], 0.f);
            *(b4v*)(qb + (size_t)(nt * 16 + pl) * 128 + ob + mt * 16 + quad * 4) = y;
        }
    }
}

// ---------------------------------------------------------------------------
// Kernel 3: flash attention, transposed-sim register pipeline + LDS-staged K/V.
//   Per 64-key chunk: ktile [64 keys][128c] (row stride 272 B, pad 16) and
//   vtile [128c][64 keys] (row stride 136 B, pad 8) staged with coalesced
//   global loads; next chunk's loads overlap compute (register prefetch).
//   GEMM1 A-frags: ds_read_b128 from ktile (bank-floor-exact).
//   GEMM2 B-frags: paired ds_read_b64 from vtile, permuted key order matching
//   the packed-P register A-frags (same permutation as R4).
// grid (HW/64, B), 256 threads.
// ---------------------------------------------------------------------------
#define KSTRIDE 272
#define VSTRIDE 136
__global__ __launch_bounds__(256) void attn_kernel(
    const bf16* __restrict__ qbuf, const bf16* __restrict__ kbuf, const bf16* __restrict__ vbuf,
    const int* __restrict__ mask, bf16* __restrict__ ctxbuf)
{
    __shared__ __align__(16) float bias[K_];
    __shared__ __align__(16) char ktile[64 * KSTRIDE];
    __shared__ __align__(16) char vtile[128 * VSTRIDE];

    const int t    = threadIdx.x;
    const int w    = t >> 6;
    const int lane = t & 63;
    const int m    = lane & 15;
    const int quad = lane >> 4;
    const int q0   = blockIdx.x * 64;
    const int b    = blockIdx.y;

    for (int i = t; i < K_; i += 256)
        bias[i] = (mask[b * K_ + i] != 0) ? 0.f : NEG_;

    // B-frags of q: lane m -> query q0+w*16+m, 4 K-steps of 32 channels
    b8v qf[4];
    {
        const bf16* qrow = qbuf + ((size_t)b * HW_ + q0 + w * 16 + m) * 128;
#pragma unroll
        for (int s = 0; s < 4; ++s) qf[s] = ldb8(qrow + s * 32 + quad * 8);
    }

    const bf16* kb = kbuf + (size_t)b * K_ * 128;
    const bf16* vb = vbuf + (size_t)b * 128 * K_;

    float4 kst[4], vst[4];
    auto load_tiles = [&](int k0) {
        const char* kg = (const char*)(kb + (size_t)k0 * 128);   // contiguous 16 KB
#pragma unroll
        for (int i = 0; i < 4; ++i)
            kst[i] = *(const float4*)(kg + (t + i * 256) * 16);
#pragma unroll
        for (int i = 0; i < 4; ++i) {
            const int ch = t + i * 256, c = ch >> 3, pos = ch & 7;
            vst[i] = *(const float4*)((const char*)(vb + (size_t)c * K_ + k0) + pos * 16);
        }
    };

    f4v acc[8];
#pragma unroll
    for (int i = 0; i < 8; ++i) acc[i] = (f4v){0.f, 0.f, 0.f, 0.f};
    float mrun = -3.0e38f, lrun = 0.f;

    load_tiles(0);
    __syncthreads();    // bias ready (also pre-stage barrier for chunk 0)

    for (int chunk = 0; chunk < 16; ++chunk) {
        const int k0 = chunk * 64;

        // ---- write staged regs to LDS
#pragma unroll
        for (int i = 0; i < 4; ++i) {
            const int ch = t + i * 256, r = ch >> 4, pos = ch & 15;
            *(float4*)(ktile + r * KSTRIDE + pos * 16) = kst[i];
        }
#pragma unroll
        for (int i = 0; i < 4; ++i) {
            const int ch = t + i * 256, c = ch >> 3, pos = ch & 7;
            *(float4*)(vtile + c * VSTRIDE + pos * 16) = vst[i];
        }
        __syncthreads();
        if (chunk < 15) load_tiles(k0 + 64);   // overlap next chunk's globals

        // ---- GEMM1: simT tiles. sv[kt][r] = sim[key=k0+kt*16+quad*4+r][q=m]
        f4v sv[4];
#pragma unroll
        for (int kt = 0; kt < 4; ++kt) {
            f4v a = (f4v){0.f, 0.f, 0.f, 0.f};
            const char* krow = ktile + (kt * 16 + m) * KSTRIDE + quad * 16;
#pragma unroll
            for (int s = 0; s < 4; ++s)
                a = __builtin_amdgcn_mfma_f32_16x16x32_bf16(ldb8(krow + s * 64), qf[s], a, 0, 0, 0);
            const float4 b4 = *(const float4*)&bias[k0 + kt * 16 + quad * 4];
            const float bb4[4] = {b4.x, b4.y, b4.z, b4.w};
#pragma unroll
            for (int r = 0; r < 4; ++r) sv[kt][r] = a[r] * SCALE_ + bb4[r];
        }

        // ---- online softmax (all 16 values in lane share q = m)
        float mloc = sv[0][0];
#pragma unroll
        for (int kt = 0; kt < 4; ++kt)
#pragma unroll
            for (int r = 0; r < 4; ++r) mloc = fmaxf(mloc, sv[kt][r]);
        mloc = fmaxf(mloc, __shfl_xor(mloc, 16, 64));
        mloc = fmaxf(mloc, __shfl_xor(mloc, 32, 64));
        const float mn = fmaxf(mrun, mloc);
        const float alpha = __expf(mrun - mn);
        mrun = mn;

        b4v pk[4];
        float rs = 0.f;
#pragma unroll
        for (int kt = 0; kt < 4; ++kt)
#pragma unroll
            for (int r = 0; r < 4; ++r) {
                const float p = __expf(sv[kt][r] - mn);
                rs += p;
                pk[kt][r] = (__bf16)p;
            }
        rs += __shfl_xor(rs, 16, 64);
        rs += __shfl_xor(rs, 32, 64);
        lrun = lrun * alpha + rs;

        float alr[4];
#pragma unroll
        for (int r = 0; r < 4; ++r) alr[r] = __shfl(alpha, quad * 4 + r, 64);
#pragma unroll
        for (int ct = 0; ct < 8; ++ct)
#pragma unroll
            for (int r = 0; r < 4; ++r) acc[ct][r] *= alr[r];

        // ---- GEMM2: ctx += P @ v (A = packed P regs, permuted key order)
        const b8v A0 = __builtin_shufflevector(pk[0], pk[1], 0, 1, 2, 3, 4, 5, 6, 7);
        const b8v A1 = __builtin_shufflevector(pk[2], pk[3], 0, 1, 2, 3, 4, 5, 6, 7);
#pragma unroll
        for (int ct = 0; ct < 8; ++ct) {
            const char* vrow = vtile + (ct * 16 + m) * VSTRIDE + quad * 8;
            const b8v B0 = __builtin_shufflevector(ldb4(vrow),      ldb4(vrow + 32), 0, 1, 2, 3, 4, 5, 6, 7);
            const b8v B1 = __builtin_shufflevector(ldb4(vrow + 64), ldb4(vrow + 96), 0, 1, 2, 3, 4, 5, 6, 7);
            acc[ct] = __builtin_amdgcn_mfma_f32_16x16x32_bf16(A0, B0, acc[ct], 0, 0, 0);
            acc[ct] = __builtin_amdgcn_mfma_f32_16x16x32_bf16(A1, B1, acc[ct], 0, 0, 0);
        }
        __syncthreads();   // all reads done before next chunk's ds_writes
    }

    // ---- epilogue: acc row q = quad*4+r, col c = ct*16+m
    float inv[4];
#pragma unroll
    for (int r = 0; r < 4; ++r) inv[r] = 1.f / __shfl(lrun, quad * 4 + r, 64);
    bf16* crow = ctxbuf + ((size_t)b * HW_ + q0 + w * 16) * 128;
#pragma unroll
    for (int ct = 0; ct < 8; ++ct)
#pragma unroll
        for (int r = 0; r < 4; ++r)
            crow[(size_t)(quad * 4 + r) * 128 + ct * 16 + m] = __float2bfloat16(acc[ct][r] * inv[r]);
}

// ---------------------------------------------------------------------------
// Final: ctx2 = relu(Wo'@ctx + bo); out = relu(Wb'@[ctx2;qt] + bb) via MFMA.
// ---------------------------------------------------------------------------
__global__ __launch_bounds__(256, 2) void final_kernel(
    const bf16* __restrict__ ctx, const bf16* __restrict__ qt,
    const __bf16* __restrict__ Wop, const float* __restrict__ bo,
    const __bf16* __restrict__ Wbp, const float* __restrict__ bb,
    float* __restrict__ out)
{
    __shared__ __bf16 Ys[128 * 136];
    const int t = threadIdx.x, w = t >> 6, lane = t & 63;
    const int pl = lane & 15, quad = lane >> 4;
    const int n0 = blockIdx.x * 128, b = blockIdx.y;
    const int ob = 32 * w;

    b8v Wof[2][4];
#pragma unroll
    for (int mt = 0; mt < 2; ++mt)
#pragma unroll
        for (int s = 0; s < 4; ++s)
            Wof[mt][s] = ldb8(Wop + (ob + mt * 16 + pl) * 128 + s * 32 + quad * 8);

    const bf16* cb = ctx + ((size_t)b * HW_ + n0) * 128;

    f4v acc1[2][8];
#pragma unroll
    for (int mt = 0; mt < 2; ++mt)
#pragma unroll
        for (int nt = 0; nt < 8; ++nt) acc1[mt][nt] = (f4v){0.f, 0.f, 0.f, 0.f};

#pragma unroll
    for (int s = 0; s < 4; ++s) {
        b8v Bf[8];
#pragma unroll
        for (int nt = 0; nt < 8; ++nt)
            Bf[nt] = ldb8(cb + (size_t)(nt * 16 + pl) * 128 + s * 32 + quad * 8);
#pragma unroll
        for (int mt = 0; mt < 2; ++mt)
#pragma unroll
            for (int nt = 0; nt < 8; ++nt)
                acc1[mt][nt] = __builtin_amdgcn_mfma_f32_16x16x32_bf16(Wof[mt][s], Bf[nt], acc1[mt][nt], 0, 0, 0);
    }

#pragma unroll
    for (int mt = 0; mt < 2; ++mt) {
        const float4 s4 = *(const float4*)(bo + ob + mt * 16 + quad * 4);
        const float shf[4] = {s4.x, s4.y, s4.z, s4.w};
#pragma unroll
        for (int nt = 0; nt < 8; ++nt) {
            b4v y;
#pragma unroll
            for (int r = 0; r < 4; ++r) y[r] = (__bf16)fmaxf(acc1[mt][nt][r] + shf[r], 0.f);
            *(b4v*)&Ys[(nt * 16 + pl) * 136 + ob + mt * 16 + quad * 4] = y;
        }
    }
    __syncthreads();

    const bf16* qtb = qt + ((size_t)b * HW_ + n0) * 128;
    f4v acc2[4][8];
#pragma unroll
    for (int mt = 0; mt < 4; ++mt)
#pragma unroll
        for (int nt = 0; nt < 8; ++nt) acc2[mt][nt] = (f4v){0.f, 0.f, 0.f, 0.f};

#pragma unroll
    for (int ks = 0; ks < 8; ++ks) {
        b8v Af[4];
#pragma unroll
        for (int mt = 0; mt < 4; ++mt)
            Af[mt] = ldb8(Wbp + (64 * w + mt * 16 + pl) * 256 + ks * 32 + quad * 8);
        b8v Bf[8];
        if (ks < 4) {
#pragma unroll
            for (int nt = 0; nt < 8; ++nt)
                Bf[nt] = *(const b8v*)&Ys[(nt * 16 + pl) * 136 + ks * 32 + quad * 8];
        } else {
#pragma unroll
            for (int nt = 0; nt < 8; ++nt)
                Bf[nt] = ldb8(qtb + (size_t)(nt * 16 + pl) * 128 + (ks - 4) * 32 + quad * 8);
        }
#pragma unroll
        for (int mt = 0; mt < 4; ++mt)
#pragma unroll
            for (int nt = 0; nt < 8; ++nt)
                acc2[mt][nt] = __builtin_amdgcn_mfma_f32_16x16x32_bf16(Af[mt], Bf[nt], acc2[mt][nt], 0, 0, 0);
    }

#pragma unroll
    for (int mt = 0; mt < 4; ++mt) {
        const float4 s4 = *(const float4*)(bb + 64 * w + mt * 16 + quad * 4);
        const float shf[4] = {s4.x, s4.y, s4.z, s4.w};
#pragma unroll
        for (int nt = 0; nt < 8; ++nt)
#pragma unroll
            for (int r = 0; r < 4; ++r)
                out[(size_t)(b * 256 + 64 * w + mt * 16 + quad * 4 + r) * HW_ + n0 + nt * 16 + pl]
                    = fmaxf(acc2[mt][nt][r] + shf[r], 0.f);
    }
}

// ---------------------------------------------------------------------------
extern "C" void kernel_launch(void* const* d_in, const int* in_sizes, int n_in,
                              void* d_out, int out_size, void* d_ws, size_t ws_size,
                              hipStream_t stream)
{
    const float* query = (const float*)d_in[0];
    const float* key   = (const float*)d_in[1];
    const float* val   = (const float*)d_in[2];
    const int*   mask  = (const int*)  d_in[3];
    const float* Wq1 = (const float*)d_in[4];  const float* sq1 = (const float*)d_in[5];  const float* bq1 = (const float*)d_in[6];
    const float* Wq2 = (const float*)d_in[7];  const float* sq2 = (const float*)d_in[8];  const float* bq2 = (const float*)d_in[9];
    const float* Wk1 = (const float*)d_in[10]; const float* sk1 = (const float*)d_in[11]; const float* bk1 = (const float*)d_in[12];
    const float* Wk2 = (const float*)d_in[13]; const float* sk2 = (const float*)d_in[14]; const float* bk2 = (const float*)d_in[15];
    const float* Wv  = (const float*)d_in[16]; const float* sv  = (const float*)d_in[17]; const float* bv  = (const float*)d_in[18];
    const float* Wo  = (const float*)d_in[19]; const float* so  = (const float*)d_in[20]; const float* bo  = (const float*)d_in[21];
    const float* Wb  = (const float*)d_in[22]; const float* sb  = (const float*)d_in[23]; const float* bb  = (const float*)d_in[24];

    char* ws = (char*)d_ws;
    bf16*   kbuf = (bf16*)(ws);                        // [B][K][C] bf16  : 1 MB
    bf16*   vbuf = (bf16*)(ws + (1u << 20));           // [B][C][K] bf16  : 1 MB
    bf16*   qbuf = (bf16*)(ws + (2u << 20));           // [B][HW][C] bf16 : 16 MB
    bf16*   ctxb = (bf16*)(ws + (18u << 20));          // [B][HW][C] bf16 : 16 MB
    bf16*   qt   = (bf16*)(ws + (34u << 20));          // [B][HW][C] bf16 : 16 MB
    __bf16* Wq1p = (__bf16*)(ws + (50u << 20));                  // 32 KB
    __bf16* Wq2p = (__bf16*)(ws + (50u << 20) + (32u << 10));    // 32 KB
    __bf16* Wop  = (__bf16*)(ws + (50u << 20) + (64u << 10));    // 32 KB
    __bf16* Wbp  = (__bf16*)(ws + (50u << 20) + (96u << 10));    // 128 KB
    float* outp = (float*)d_out;

    wprep_kernel<<<448, 256, 0, stream>>>(Wq1, sq1, Wq2, sq2, Wo, so, Wb, sb,
                                          Wq1p, Wq2p, Wop, Wbp);
    tq_kernel<<<dim3(HW_ / 64, B_), 256, 0, stream>>>(query, qt);
    kv_proj_kernel<<<dim3(K_ / 32, B_), 256, 0, stream>>>(
        key, val, Wk1, sk1, bk1, Wk2, sk2, bk2, Wv, sv, bv, kbuf, vbuf);
    qproj_kernel<<<dim3(HW_ / 128, B_), 256, 0, stream>>>(
        qt, Wq1p, bq1, Wq2p, bq2, qbuf);
    attn_kernel<<<dim3(HW_ / 64, B_), 256, 0, stream>>>(
        qbuf, kbuf, vbuf, mask, ctxb);
    final_kernel<<<dim3(HW_ / 128, B_), 256, 0, stream>>>(
        ctxb, qt, Wop, bo, Wbp, bb, outp);
}

// Round 6
// 285.371 us; speedup vs baseline: 1.9506x; 1.4387x over previous
//
#include <hip/hip_runtime.h>
#include <hip/hip_bf16.h>

#define B_    4
#define C_    128
#define HW_   16384
#define K_    1024
#define NEG_  (-10000000.0f)
#define SCALE_ 0.08838834764831845f   // 128^-0.5

using bf16 = __hip_bfloat16;
typedef __bf16 b8v __attribute__((ext_vector_type(8)));
typedef __bf16 b4v __attribute__((ext_vector_type(4)));
typedef __bf16 b2v __attribute__((ext_vector_type(2)));
typedef float  f4v __attribute__((ext_vector_type(4)));

__device__ __forceinline__ b8v ldb8(const void* p) { return *(const b8v*)p; }
__device__ __forceinline__ b4v ldb4(const void* p) { return *(const b4v*)p; }
__device__ __forceinline__ void storev(float* p, float v) { *p = v; }
__device__ __forceinline__ void storev(bf16* p, float v)  { *p = __float2bfloat16(v); }

// ---------------------------------------------------------------------------
// Weight prep: fold BN scale into rows, convert fp32 -> bf16.
// ---------------------------------------------------------------------------
__global__ __launch_bounds__(256) void wprep_kernel(
    const float* __restrict__ Wq1, const float* __restrict__ sq1,
    const float* __restrict__ Wq2, const float* __restrict__ sq2,
    const float* __restrict__ Wo,  const float* __restrict__ so,
    const float* __restrict__ Wb,  const float* __restrict__ sb,
    __bf16* __restrict__ Wq1p, __bf16* __restrict__ Wq2p,
    __bf16* __restrict__ Wop,  __bf16* __restrict__ Wbp)
{
    const int idx = blockIdx.x * 256 + threadIdx.x;
    if (idx < 16384)      { Wq1p[idx] = (__bf16)(Wq1[idx] * sq1[idx >> 7]); }
    else if (idx < 32768) { const int i = idx - 16384; Wq2p[i] = (__bf16)(Wq2[i] * sq2[i >> 7]); }
    else if (idx < 49152) { const int i = idx - 32768; Wop[i]  = (__bf16)(Wo[i]  * so[i >> 7]); }
    else                  { const int i = idx - 49152; Wbp[i]  = (__bf16)(Wb[i]  * sb[i >> 8]); }
}

// ---------------------------------------------------------------------------
// Transpose query [b][c][p] fp32 -> qt [b][p][c] bf16. grid (HW/64, B).
// ---------------------------------------------------------------------------
__global__ __launch_bounds__(256) void tq_kernel(const float* __restrict__ query,
                                                 bf16* __restrict__ qt)
{
    __shared__ float Xs[64 * 129];
    const int p0 = blockIdx.x * 64, b = blockIdx.y, t = threadIdx.x;
    const int pl = t & 63, cg = t >> 6;
#pragma unroll 4
    for (int i = 0; i < 32; ++i) {
        const int c = cg * 32 + i;
        Xs[pl * 129 + c] = query[(size_t)(b * 128 + c) * HW_ + p0 + pl];
    }
    __syncthreads();
#pragma unroll 4
    for (int it = 0; it < 16; ++it) {
        const int p = it * 4 + cg;
        b2v pk;
        pk[0] = (__bf16)Xs[p * 129 + 2 * pl];
        pk[1] = (__bf16)Xs[p * 129 + 2 * pl + 1];
        *(b2v*)(qt + ((size_t)b * HW_ + p0 + p) * 128 + 2 * pl) = pk;
    }
}

// ---------------------------------------------------------------------------
// kv_proj: k (2 layers) -> kbuf [b][k][c] bf16 ; v (1 layer) -> vbuf [b][c][k].
// ---------------------------------------------------------------------------
__device__ __forceinline__ void layer128_lds(const float* __restrict__ Xs, float* __restrict__ Ysh,
                                             const float* __restrict__ W,
                                             const float* __restrict__ sc, const float* __restrict__ sh)
{
    const int t = threadIdx.x;
    const int o = t & 127;
    const int half = t >> 7;
    float acc[16];
#pragma unroll
    for (int p = 0; p < 16; ++p) acc[p] = 0.f;
    const float* wrow  = W + o * 128;
    const float* xbase = Xs + half * 16;
    for (int c = 0; c < 128; c += 4) {
        const float4 w4 = *(const float4*)(wrow + c);
        const float wj[4] = {w4.x, w4.y, w4.z, w4.w};
#pragma unroll
        for (int j = 0; j < 4; ++j) {
            const float* xr = xbase + (c + j) * 33;
#pragma unroll
            for (int p = 0; p < 16; ++p) acc[p] += wj[j] * xr[p];
        }
    }
    const float s = sc[o], h = sh[o];
    float* yb = Ysh + o * 33 + half * 16;
#pragma unroll
    for (int p = 0; p < 16; ++p) yb[p] = fmaxf(fmaf(s, acc[p], h), 0.f);
}

template <typename OutT>
__device__ __forceinline__ void layer128_store(const float* __restrict__ Xs, OutT* __restrict__ outp,
                                               const float* __restrict__ W,
                                               const float* __restrict__ sc, const float* __restrict__ sh)
{
    const int t = threadIdx.x;
    const int o = t & 127;
    const int half = t >> 7;
    float acc[16];
#pragma unroll
    for (int p = 0; p < 16; ++p) acc[p] = 0.f;
    const float* wrow  = W + o * 128;
    const float* xbase = Xs + half * 16;
    for (int c = 0; c < 128; c += 4) {
        const float4 w4 = *(const float4*)(wrow + c);
        const float wj[4] = {w4.x, w4.y, w4.z, w4.w};
#pragma unroll
        for (int j = 0; j < 4; ++j) {
            const float* xr = xbase + (c + j) * 33;
#pragma unroll
            for (int p = 0; p < 16; ++p) acc[p] += wj[j] * xr[p];
        }
    }
    const float s = sc[o], h = sh[o];
#pragma unroll
    for (int p = 0; p < 16; ++p) {
        float v = fmaxf(fmaf(s, acc[p], h), 0.f);
        storev(&outp[(size_t)(half * 16 + p) * 128 + o], v);
    }
}

__global__ __launch_bounds__(256) void kv_proj_kernel(
    const float* __restrict__ key, const float* __restrict__ val,
    const float* __restrict__ Wk1, const float* __restrict__ sk1, const float* __restrict__ bk1,
    const float* __restrict__ Wk2, const float* __restrict__ sk2, const float* __restrict__ bk2,
    const float* __restrict__ Wv,  const float* __restrict__ sv,  const float* __restrict__ bv,
    bf16* __restrict__ kbuf, bf16* __restrict__ vbuf)
{
    __shared__ __align__(16) float X[128 * 33];
    __shared__ __align__(16) float Y[128 * 33];
    const int p0 = blockIdx.x * 32;
    const int b  = blockIdx.y;
    const int t  = threadIdx.x;

    for (int e = t; e < 4096; e += 256) {
        int c = e >> 5, p = e & 31;
        X[c * 33 + p] = key[(size_t)(b * 128 + c) * K_ + p0 + p];
    }
    __syncthreads();
    layer128_lds(X, Y, Wk1, sk1, bk1);
    __syncthreads();
    layer128_store(Y, kbuf + (size_t)(b * K_ + p0) * 128, Wk2, sk2, bk2);
    __syncthreads();
    for (int e = t; e < 4096; e += 256) {
        int c = e >> 5, p = e & 31;
        X[c * 33 + p] = val[(size_t)(b * 128 + c) * K_ + p0 + p];
    }
    __syncthreads();
    layer128_lds(X, Y, Wv, sv, bv);
    __syncthreads();
    for (int e = t; e < 4096; e += 256) {
        int c = e >> 5, p = e & 31;
        vbuf[(size_t)(b * 128 + c) * K_ + p0 + p] = __float2bfloat16(Y[c * 33 + p]);
    }
}

// ---------------------------------------------------------------------------
// q projection via MFMA (unchanged). grid (HW/128, B).
// ---------------------------------------------------------------------------
__global__ __launch_bounds__(256, 2) void qproj_kernel(
    const bf16* __restrict__ qt,
    const __bf16* __restrict__ W1, const float* __restrict__ sh1,
    const __bf16* __restrict__ W2, const float* __restrict__ sh2,
    bf16* __restrict__ qbuf)
{
    __shared__ __bf16 Ys[128 * 136];
    const int t = threadIdx.x, w = t >> 6, lane = t & 63;
    const int pl = lane & 15, quad = lane >> 4;
    const int n0 = blockIdx.x * 128, b = blockIdx.y;
    const int ob = 32 * w;

    b8v W1f[2][4], W2f[2][4];
#pragma unroll
    for (int mt = 0; mt < 2; ++mt)
#pragma unroll
        for (int s = 0; s < 4; ++s) {
            W1f[mt][s] = ldb8(W1 + (ob + mt * 16 + pl) * 128 + s * 32 + quad * 8);
            W2f[mt][s] = ldb8(W2 + (ob + mt * 16 + pl) * 128 + s * 32 + quad * 8);
        }

    const bf16* qtb = qt + ((size_t)b * HW_ + n0) * 128;

    f4v acc[2][8];
#pragma unroll
    for (int mt = 0; mt < 2; ++mt)
#pragma unroll
        for (int nt = 0; nt < 8; ++nt) acc[mt][nt] = (f4v){0.f, 0.f, 0.f, 0.f};

#pragma unroll
    for (int s = 0; s < 4; ++s) {
        b8v Bf[8];
#pragma unroll
        for (int nt = 0; nt < 8; ++nt)
            Bf[nt] = ldb8(qtb + (size_t)(nt * 16 + pl) * 128 + s * 32 + quad * 8);
#pragma unroll
        for (int mt = 0; mt < 2; ++mt)
#pragma unroll
            for (int nt = 0; nt < 8; ++nt)
                acc[mt][nt] = __builtin_amdgcn_mfma_f32_16x16x32_bf16(W1f[mt][s], Bf[nt], acc[mt][nt], 0, 0, 0);
    }

#pragma unroll
    for (int mt = 0; mt < 2; ++mt) {
        const float4 s4 = *(const float4*)(sh1 + ob + mt * 16 + quad * 4);
        const float shf[4] = {s4.x, s4.y, s4.z, s4.w};
#pragma unroll
        for (int nt = 0; nt < 8; ++nt) {
            b4v y;
#pragma unroll
            for (int r = 0; r < 4; ++r) y[r] = (__bf16)fmaxf(acc[mt][nt][r] + shf[r], 0.f);
            *(b4v*)&Ys[(nt * 16 + pl) * 136 + ob + mt * 16 + quad * 4] = y;
        }
    }
    __syncthreads();

    f4v acc2[2][8];
#pragma unroll
    for (int mt = 0; mt < 2; ++mt)
#pragma unroll
        for (int nt = 0; nt < 8; ++nt) acc2[mt][nt] = (f4v){0.f, 0.f, 0.f, 0.f};

#pragma unroll
    for (int s = 0; s < 4; ++s) {
        b8v Bf[8];
#pragma unroll
        for (int nt = 0; nt < 8; ++nt)
            Bf[nt] = *(const b8v*)&Ys[(nt * 16 + pl) * 136 + s * 32 + quad * 8];
#pragma unroll
        for (int mt = 0; mt < 2; ++mt)
#pragma unroll
            for (int nt = 0; nt < 8; ++nt)
                acc2[mt][nt] = __builtin_amdgcn_mfma_f32_16x16x32_bf16(W2f[mt][s], Bf[nt], acc2[mt][nt], 0, 0, 0);
    }

    bf16* qb = qbuf + ((size_t)b * HW_ + n0) * 128;
#pragma unroll
    for (int mt = 0; mt < 2; ++mt) {
        const float4 s4 = *(const float4*)(sh2 + ob + mt * 16 + quad * 4);
        const float shf[4] = {s4.x, s4.y, s4.z, s4.w};
#pragma unroll
        for (int nt = 0; nt < 8; ++nt) {
            b4v y;
#pragma unroll
            for (int r = 0; r < 4; ++r) y[r] = (__bf16)fmaxf(acc2[mt][nt][r] + shf[r], 0.f);
            *(b4v*)(qb + (size_t)(nt * 16 + pl) * 128 + ob + mt * 16 + quad * 4) = y;
        }
    }
}

// ---------------------------------------------------------------------------
// Kernel 3: flash attention. R5 structure, spill-free staging:
// 8 named float4 registers, loop-invariant pointers, no lambda/arrays.
// grid (HW/64, B), 256 threads.
// ---------------------------------------------------------------------------
#define KSTRIDE 272
#define VSTRIDE 136
__global__ __launch_bounds__(256, 2) void attn_kernel(
    const bf16* __restrict__ qbuf, const bf16* __restrict__ kbuf, const bf16* __restrict__ vbuf,
    const int* __restrict__ mask, bf16* __restrict__ ctxbuf)
{
    __shared__ __align__(16) float bias[K_];
    __shared__ __align__(16) char ktile[64 * KSTRIDE];
    __shared__ __align__(16) char vtile[128 * VSTRIDE];

    const int t    = threadIdx.x;
    const int w    = t >> 6;
    const int lane = t & 63;
    const int m    = lane & 15;
    const int quad = lane >> 4;
    const int q0   = blockIdx.x * 64;
    const int b    = blockIdx.y;

    for (int i = t; i < K_; i += 256)
        bias[i] = (mask[b * K_ + i] != 0) ? 0.f : NEG_;

    // B-frags of q: lane m -> query q0+w*16+m, 4 K-steps of 32 channels
    b8v qf[4];
    {
        const bf16* qrow = qbuf + ((size_t)b * HW_ + q0 + w * 16 + m) * 128;
#pragma unroll
        for (int s = 0; s < 4; ++s) qf[s] = ldb8(qrow + s * 32 + quad * 8);
    }

    const bf16* kpt = kbuf + (size_t)b * K_ * 128;
    const bf16* vpt = vbuf + (size_t)b * 128 * K_;

    // loop-invariant global source pointers (byte-based)
    const char* kg = (const char*)kpt + t * 16;                                  // + chunk*16384 + i*4096
    const char* vg = (const char*)(vpt + (size_t)(t >> 3) * K_) + (t & 7) * 16;  // + chunk*128  + i*65536
    // loop-invariant LDS dest pointers
    char* kl = ktile + (t >> 4) * KSTRIDE + (t & 15) * 16;   // + i*16*KSTRIDE
    char* vl = vtile + (t >> 3) * VSTRIDE + (t & 7) * 16;    // + i*32*VSTRIDE

    // staged registers (individually named -> guaranteed SROA)
    float4 k_r0 = *(const float4*)(kg);
    float4 k_r1 = *(const float4*)(kg + 4096);
    float4 k_r2 = *(const float4*)(kg + 8192);
    float4 k_r3 = *(const float4*)(kg + 12288);
    float4 v_r0 = *(const float4*)(vg);
    float4 v_r1 = *(const float4*)(vg + 65536);
    float4 v_r2 = *(const float4*)(vg + 131072);
    float4 v_r3 = *(const float4*)(vg + 196608);

    f4v acc[8];
#pragma unroll
    for (int i = 0; i < 8; ++i) acc[i] = (f4v){0.f, 0.f, 0.f, 0.f};
    float mrun = -3.0e38f, lrun = 0.f;

    for (int chunk = 0; chunk < 16; ++chunk) {
        const int k0 = chunk * 64;

        // ---- write staged regs to LDS
        *(float4*)(kl)                = k_r0;
        *(float4*)(kl + 16 * KSTRIDE) = k_r1;
        *(float4*)(kl + 32 * KSTRIDE) = k_r2;
        *(float4*)(kl + 48 * KSTRIDE) = k_r3;
        *(float4*)(vl)                = v_r0;
        *(float4*)(vl + 32 * VSTRIDE) = v_r1;
        *(float4*)(vl + 64 * VSTRIDE) = v_r2;
        *(float4*)(vl + 96 * VSTRIDE) = v_r3;
        __syncthreads();

        // ---- prefetch next chunk's globals (overlaps compute below)
        if (chunk < 15) {
            const char* kgn = kg + (chunk + 1) * 16384;
            const char* vgn = vg + (chunk + 1) * 128;
            k_r0 = *(const float4*)(kgn);
            k_r1 = *(const float4*)(kgn + 4096);
            k_r2 = *(const float4*)(kgn + 8192);
            k_r3 = *(const float4*)(kgn + 12288);
            v_r0 = *(const float4*)(vgn);
            v_r1 = *(const float4*)(vgn + 65536);
            v_r2 = *(const float4*)(vgn + 131072);
            v_r3 = *(const float4*)(vgn + 196608);
        }

        // ---- GEMM1: simT tiles. sv[kt][r] = sim[key=k0+kt*16+quad*4+r][q=m]
        f4v sv[4];
#pragma unroll
        for (int kt = 0; kt < 4; ++kt) {
            f4v a = (f4v){0.f, 0.f, 0.f, 0.f};
            const char* krow = ktile + (kt * 16 + m) * KSTRIDE + quad * 16;
#pragma unroll
            for (int s = 0; s < 4; ++s)
                a = __builtin_amdgcn_mfma_f32_16x16x32_bf16(ldb8(krow + s * 64), qf[s], a, 0, 0, 0);
            const float4 b4 = *(const float4*)&bias[k0 + kt * 16 + quad * 4];
            const float bb4[4] = {b4.x, b4.y, b4.z, b4.w};
#pragma unroll
            for (int r = 0; r < 4; ++r) sv[kt][r] = a[r] * SCALE_ + bb4[r];
        }

        // ---- online softmax (all 16 values in lane share q = m)
        float mloc = sv[0][0];
#pragma unroll
        for (int kt = 0; kt < 4; ++kt)
#pragma unroll
            for (int r = 0; r < 4; ++r) mloc = fmaxf(mloc, sv[kt][r]);
        mloc = fmaxf(mloc, __shfl_xor(mloc, 16, 64));
        mloc = fmaxf(mloc, __shfl_xor(mloc, 32, 64));
        const float mn = fmaxf(mrun, mloc);
        const float alpha = __expf(mrun - mn);
        mrun = mn;

        b4v pk[4];
        float rs = 0.f;
#pragma unroll
        for (int kt = 0; kt < 4; ++kt)
#pragma unroll
            for (int r = 0; r < 4; ++r) {
                const float p = __expf(sv[kt][r] - mn);
                rs += p;
                pk[kt][r] = (__bf16)p;
            }
        rs += __shfl_xor(rs, 16, 64);
        rs += __shfl_xor(rs, 32, 64);
        lrun = lrun * alpha + rs;

        float alr[4];
#pragma unroll
        for (int r = 0; r < 4; ++r) alr[r] = __shfl(alpha, quad * 4 + r, 64);
#pragma unroll
        for (int ct = 0; ct < 8; ++ct)
#pragma unroll
            for (int r = 0; r < 4; ++r) acc[ct][r] *= alr[r];

        // ---- GEMM2: ctx += P @ v (A = packed P regs, permuted key order)
        const b8v A0 = __builtin_shufflevector(pk[0], pk[1], 0, 1, 2, 3, 4, 5, 6, 7);
        const b8v A1 = __builtin_shufflevector(pk[2], pk[3], 0, 1, 2, 3, 4, 5, 6, 7);
#pragma unroll
        for (int ct = 0; ct < 8; ++ct) {
            const char* vrow = vtile + (ct * 16 + m) * VSTRIDE + quad * 8;
            const b8v B0 = __builtin_shufflevector(ldb4(vrow),      ldb4(vrow + 32), 0, 1, 2, 3, 4, 5, 6, 7);
            const b8v B1 = __builtin_shufflevector(ldb4(vrow + 64), ldb4(vrow + 96), 0, 1, 2, 3, 4, 5, 6, 7);
            acc[ct] = __builtin_amdgcn_mfma_f32_16x16x32_bf16(A0, B0, acc[ct], 0, 0, 0);
            acc[ct] = __builtin_amdgcn_mfma_f32_16x16x32_bf16(A1, B1, acc[ct], 0, 0, 0);
        }
        __syncthreads();   // all reads done before next chunk's ds_writes
    }

    // ---- epilogue: acc row q = quad*4+r, col c = ct*16+m
    float inv[4];
#pragma unroll
    for (int r = 0; r < 4; ++r) inv[r] = 1.f / __shfl(lrun, quad * 4 + r, 64);
    bf16* crow = ctxbuf + ((size_t)b * HW_ + q0 + w * 16) * 128;
#pragma unroll
    for (int ct = 0; ct < 8; ++ct)
#pragma unroll
        for (int r = 0; r < 4; ++r)
            crow[(size_t)(quad * 4 + r) * 128 + ct * 16 + m] = __float2bfloat16(acc[ct][r] * inv[r]);
}

// ---------------------------------------------------------------------------
// Final: ctx2 = relu(Wo'@ctx + bo); out = relu(Wb'@[ctx2;qt] + bb) via MFMA.
// ---------------------------------------------------------------------------
__global__ __launch_bounds__(256, 2) void final_kernel(
    const bf16* __restrict__ ctx, const bf16* __restrict__ qt,
    const __bf16* __restrict__ Wop, const float* __restrict__ bo,
    const __bf16* __restrict__ Wbp, const float* __restrict__ bb,
    float* __restrict__ out)
{
    __shared__ __bf16 Ys[128 * 136];
    const int t = threadIdx.x, w = t >> 6, lane = t & 63;
    const int pl = lane & 15, quad = lane >> 4;
    const int n0 = blockIdx.x * 128, b = blockIdx.y;
    const int ob = 32 * w;

    b8v Wof[2][4];
#pragma unroll
    for (int mt = 0; mt < 2; ++mt)
#pragma unroll
        for (int s = 0; s < 4; ++s)
            Wof[mt][s] = ldb8(Wop + (ob + mt * 16 + pl) * 128 + s * 32 + quad * 8);

    const bf16* cb = ctx + ((size_t)b * HW_ + n0) * 128;

    f4v acc1[2][8];
#pragma unroll
    for (int mt = 0; mt < 2; ++mt)
#pragma unroll
        for (int nt = 0; nt < 8; ++nt) acc1[mt][nt] = (f4v){0.f, 0.f, 0.f, 0.f};

#pragma unroll
    for (int s = 0; s < 4; ++s) {
        b8v Bf[8];
#pragma unroll
        for (int nt = 0; nt < 8; ++nt)
            Bf[nt] = ldb8(cb + (size_t)(nt * 16 + pl) * 128 + s * 32 + quad * 8);
#pragma unroll
        for (int mt = 0; mt < 2; ++mt)
#pragma unroll
            for (int nt = 0; nt < 8; ++nt)
                acc1[mt][nt] = __builtin_amdgcn_mfma_f32_16x16x32_bf16(Wof[mt][s], Bf[nt], acc1[mt][nt], 0, 0, 0);
    }

#pragma unroll
    for (int mt = 0; mt < 2; ++mt) {
        const float4 s4 = *(const float4*)(bo + ob + mt * 16 + quad * 4);
        const float shf[4] = {s4.x, s4.y, s4.z, s4.w};
#pragma unroll
        for (int nt = 0; nt < 8; ++nt) {
            b4v y;
#pragma unroll
            for (int r = 0; r < 4; ++r) y[r] = (__bf16)fmaxf(acc1[mt][nt][r] + shf[r], 0.f);
            *(b4v*)&Ys[(nt * 16 + pl) * 136 + ob + mt * 16 + quad * 4] = y;
        }
    }
    __syncthreads();

    const bf16* qtb = qt + ((size_t)b * HW_ + n0) * 128;
    f4v acc2[4][8];
#pragma unroll
    for (int mt = 0; mt < 4; ++mt)
#pragma unroll
        for (int nt = 0; nt < 8; ++nt) acc2[mt][nt] = (f4v){0.f, 0.f, 0.f, 0.f};

#pragma unroll
    for (int ks = 0; ks < 8; ++ks) {
        b8v Af[4];
#pragma unroll
        for (int mt = 0; mt < 4; ++mt)
            Af[mt] = ldb8(Wbp + (64 * w + mt * 16 + pl) * 256 + ks * 32 + quad * 8);
        b8v Bf[8];
        if (ks < 4) {
#pragma unroll
            for (int nt = 0; nt < 8; ++nt)
                Bf[nt] = *(const b8v*)&Ys[(nt * 16 + pl) * 136 + ks * 32 + quad * 8];
        } else {
#pragma unroll
            for (int nt = 0; nt < 8; ++nt)
                Bf[nt] = ldb8(qtb + (size_t)(nt * 16 + pl) * 128 + (ks - 4) * 32 + quad * 8);
        }
#pragma unroll
        for (int mt = 0; mt < 4; ++mt)
#pragma unroll
            for (int nt = 0; nt < 8; ++nt)
                acc2[mt][nt] = __builtin_amdgcn_mfma_f32_16x16x32_bf16(Af[mt], Bf[nt], acc2[mt][nt], 0, 0, 0);
    }

#pragma unroll
    for (int mt = 0; mt < 4; ++mt) {
        const float4 s4 = *(const float4*)(bb + 64 * w + mt * 16 + quad * 4);
        const float shf[4] = {s4.x, s4.y, s4.z, s4.w};
#pragma unroll
        for (int nt = 0; nt < 8; ++nt)
#pragma unroll
            for (int r = 0; r < 4; ++r)
                out[(size_t)(b * 256 + 64 * w + mt * 16 + quad * 4 + r) * HW_ + n0 + nt * 16 + pl]
                    = fmaxf(acc2[mt][nt][r] + shf[r], 0.f);
    }
}

// ---------------------------------------------------------------------------
extern "C" void kernel_launch(void* const* d_in, const int* in_sizes, int n_in,
                              void* d_out, int out_size, void* d_ws, size_t ws_size,
                              hipStream_t stream)
{
    const float* query = (const float*)d_in[0];
    const float* key   = (const float*)d_in[1];
    const float* val   = (const float*)d_in[2];
    const int*   mask  = (const int*)  d_in[3];
    const float* Wq1 = (const float*)d_in[4];  const float* sq1 = (const float*)d_in[5];  const float* bq1 = (const float*)d_in[6];
    const float* Wq2 = (const float*)d_in[7];  const float* sq2 = (const float*)d_in[8];  const float* bq2 = (const float*)d_in[9];
    const float* Wk1 = (const float*)d_in[10]; const float* sk1 = (const float*)d_in[11]; const float* bk1 = (const float*)d_in[12];
    const float* Wk2 = (const float*)d_in[13]; const float* sk2 = (const float*)d_in[14]; const float* bk2 = (const float*)d_in[15];
    const float* Wv  = (const float*)d_in[16]; const float* sv  = (const float*)d_in[17]; const float* bv  = (const float*)d_in[18];
    const float* Wo  = (const float*)d_in[19]; const float* so  = (const float*)d_in[20]; const float* bo  = (const float*)d_in[21];
    const float* Wb  = (const float*)d_in[22]; const float* sb  = (const float*)d_in[23]; const float* bb  = (const float*)d_in[24];

    char* ws = (char*)d_ws;
    bf16*   kbuf = (bf16*)(ws);                        // [B][K][C] bf16  : 1 MB
    bf16*   vbuf = (bf16*)(ws + (1u << 20));           // [B][C][K] bf16  : 1 MB
    bf16*   qbuf = (bf16*)(ws + (2u << 20));           // [B][HW][C] bf16 : 16 MB
    bf16*   ctxb = (bf16*)(ws + (18u << 20));          // [B][HW][C] bf16 : 16 MB
    bf16*   qt   = (bf16*)(ws + (34u << 20));          // [B][HW][C] bf16 : 16 MB
    __bf16* Wq1p = (__bf16*)(ws + (50u << 20));                  // 32 KB
    __bf16* Wq2p = (__bf16*)(ws + (50u << 20) + (32u << 10));    // 32 KB
    __bf16* Wop  = (__bf16*)(ws + (50u << 20) + (64u << 10));    // 32 KB
    __bf16* Wbp  = (__bf16*)(ws + (50u << 20) + (96u << 10));    // 128 KB
    float* outp = (float*)d_out;

    wprep_kernel<<<448, 256, 0, stream>>>(Wq1, sq1, Wq2, sq2, Wo, so, Wb, sb,
                                          Wq1p, Wq2p, Wop, Wbp);
    tq_kernel<<<dim3(HW_ / 64, B_), 256, 0, stream>>>(query, qt);
    kv_proj_kernel<<<dim3(K_ / 32, B_), 256, 0, stream>>>(
        key, val, Wk1, sk1, bk1, Wk2, sk2, bk2, Wv, sv, bv, kbuf, vbuf);
    qproj_kernel<<<dim3(HW_ / 128, B_), 256, 0, stream>>>(
        qt, Wq1p, bq1, Wq2p, bq2, qbuf);
    attn_kernel<<<dim3(HW_ / 64, B_), 256, 0, stream>>>(
        qbuf, kbuf, vbuf, mask, ctxb);
    final_kernel<<<dim3(HW_ / 128, B_), 256, 0, stream>>>(
        ctxb, qt, Wop, bo, Wbp, bb, outp);
}

// Round 7
// 269.211 us; speedup vs baseline: 2.0677x; 1.0600x over previous
//
#include <hip/hip_runtime.h>
#include <hip/hip_bf16.h>

#define B_    4
#define C_    128
#define HW_   16384
#define K_    1024
#define NEG_  (-10000000.0f)
#define SCALE_ 0.08838834764831845f   // 128^-0.5

using bf16 = __hip_bfloat16;
typedef __bf16 b8v __attribute__((ext_vector_type(8)));
typedef __bf16 b4v __attribute__((ext_vector_type(4)));
typedef __bf16 b2v __attribute__((ext_vector_type(2)));
typedef float  f4v __attribute__((ext_vector_type(4)));

__device__ __forceinline__ b8v ldb8(const void* p) { return *(const b8v*)p; }
__device__ __forceinline__ b4v ldb4(const void* p) { return *(const b4v*)p; }
__device__ __forceinline__ void storev(float* p, float v) { *p = v; }
__device__ __forceinline__ void storev(bf16* p, float v)  { *p = __float2bfloat16(v); }

#define XSTRIDE 272   // 256 B row + 16 pad: b128 frag reads land on the bank floor

// ---------------------------------------------------------------------------
// Weight prep: fold BN scale into rows, convert fp32 -> bf16.
// ---------------------------------------------------------------------------
__global__ __launch_bounds__(256) void wprep_kernel(
    const float* __restrict__ Wq1, const float* __restrict__ sq1,
    const float* __restrict__ Wq2, const float* __restrict__ sq2,
    const float* __restrict__ Wo,  const float* __restrict__ so,
    const float* __restrict__ Wb,  const float* __restrict__ sb,
    __bf16* __restrict__ Wq1p, __bf16* __restrict__ Wq2p,
    __bf16* __restrict__ Wop,  __bf16* __restrict__ Wbp)
{
    const int idx = blockIdx.x * 256 + threadIdx.x;
    if (idx < 16384)      { Wq1p[idx] = (__bf16)(Wq1[idx] * sq1[idx >> 7]); }
    else if (idx < 32768) { const int i = idx - 16384; Wq2p[i] = (__bf16)(Wq2[i] * sq2[i >> 7]); }
    else if (idx < 49152) { const int i = idx - 32768; Wop[i]  = (__bf16)(Wo[i]  * so[i >> 7]); }
    else                  { const int i = idx - 49152; Wbp[i]  = (__bf16)(Wb[i]  * sb[i >> 8]); }
}

// ---------------------------------------------------------------------------
// Transpose query [b][c][p] fp32 -> qt [b][p][c] bf16. grid (HW/64, B).
// ---------------------------------------------------------------------------
__global__ __launch_bounds__(256) void tq_kernel(const float* __restrict__ query,
                                                 bf16* __restrict__ qt)
{
    __shared__ float Xs[64 * 129];
    const int p0 = blockIdx.x * 64, b = blockIdx.y, t = threadIdx.x;
    const int pl = t & 63, cg = t >> 6;
#pragma unroll 4
    for (int i = 0; i < 32; ++i) {
        const int c = cg * 32 + i;
        Xs[pl * 129 + c] = query[(size_t)(b * 128 + c) * HW_ + p0 + pl];
    }
    __syncthreads();
#pragma unroll 4
    for (int it = 0; it < 16; ++it) {
        const int p = it * 4 + cg;
        b2v pk;
        pk[0] = (__bf16)Xs[p * 129 + 2 * pl];
        pk[1] = (__bf16)Xs[p * 129 + 2 * pl + 1];
        *(b2v*)(qt + ((size_t)b * HW_ + p0 + p) * 128 + 2 * pl) = pk;
    }
}

// ---------------------------------------------------------------------------
// kv_proj: k (2 layers) -> kbuf [b][k][c] bf16 ; v (1 layer) -> vbuf [b][c][k].
// ---------------------------------------------------------------------------
__device__ __forceinline__ void layer128_lds(const float* __restrict__ Xs, float* __restrict__ Ysh,
                                             const float* __restrict__ W,
                                             const float* __restrict__ sc, const float* __restrict__ sh)
{
    const int t = threadIdx.x;
    const int o = t & 127;
    const int half = t >> 7;
    float acc[16];
#pragma unroll
    for (int p = 0; p < 16; ++p) acc[p] = 0.f;
    const float* wrow  = W + o * 128;
    const float* xbase = Xs + half * 16;
    for (int c = 0; c < 128; c += 4) {
        const float4 w4 = *(const float4*)(wrow + c);
        const float wj[4] = {w4.x, w4.y, w4.z, w4.w};
#pragma unroll
        for (int j = 0; j < 4; ++j) {
            const float* xr = xbase + (c + j) * 33;
#pragma unroll
            for (int p = 0; p < 16; ++p) acc[p] += wj[j] * xr[p];
        }
    }
    const float s = sc[o], h = sh[o];
    float* yb = Ysh + o * 33 + half * 16;
#pragma unroll
    for (int p = 0; p < 16; ++p) yb[p] = fmaxf(fmaf(s, acc[p], h), 0.f);
}

template <typename OutT>
__device__ __forceinline__ void layer128_store(const float* __restrict__ Xs, OutT* __restrict__ outp,
                                               const float* __restrict__ W,
                                               const float* __restrict__ sc, const float* __restrict__ sh)
{
    const int t = threadIdx.x;
    const int o = t & 127;
    const int half = t >> 7;
    float acc[16];
#pragma unroll
    for (int p = 0; p < 16; ++p) acc[p] = 0.f;
    const float* wrow  = W + o * 128;
    const float* xbase = Xs + half * 16;
    for (int c = 0; c < 128; c += 4) {
        const float4 w4 = *(const float4*)(wrow + c);
        const float wj[4] = {w4.x, w4.y, w4.z, w4.w};
#pragma unroll
        for (int j = 0; j < 4; ++j) {
            const float* xr = xbase + (c + j) * 33;
#pragma unroll
            for (int p = 0; p < 16; ++p) acc[p] += wj[j] * xr[p];
        }
    }
    const float s = sc[o], h = sh[o];
#pragma unroll
    for (int p = 0; p < 16; ++p) {
        float v = fmaxf(fmaf(s, acc[p], h), 0.f);
        storev(&outp[(size_t)(half * 16 + p) * 128 + o], v);
    }
}

__global__ __launch_bounds__(256) void kv_proj_kernel(
    const float* __restrict__ key, const float* __restrict__ val,
    const float* __restrict__ Wk1, const float* __restrict__ sk1, const float* __restrict__ bk1,
    const float* __restrict__ Wk2, const float* __restrict__ sk2, const float* __restrict__ bk2,
    const float* __restrict__ Wv,  const float* __restrict__ sv,  const float* __restrict__ bv,
    bf16* __restrict__ kbuf, bf16* __restrict__ vbuf)
{
    __shared__ __align__(16) float X[128 * 33];
    __shared__ __align__(16) float Y[128 * 33];
    const int p0 = blockIdx.x * 32;
    const int b  = blockIdx.y;
    const int t  = threadIdx.x;

    for (int e = t; e < 4096; e += 256) {
        int c = e >> 5, p = e & 31;
        X[c * 33 + p] = key[(size_t)(b * 128 + c) * K_ + p0 + p];
    }
    __syncthreads();
    layer128_lds(X, Y, Wk1, sk1, bk1);
    __syncthreads();
    layer128_store(Y, kbuf + (size_t)(b * K_ + p0) * 128, Wk2, sk2, bk2);
    __syncthreads();
    for (int e = t; e < 4096; e += 256) {
        int c = e >> 5, p = e & 31;
        X[c * 33 + p] = val[(size_t)(b * 128 + c) * K_ + p0 + p];
    }
    __syncthreads();
    layer128_lds(X, Y, Wv, sv, bv);
    __syncthreads();
    for (int e = t; e < 4096; e += 256) {
        int c = e >> 5, p = e & 31;
        vbuf[(size_t)(b * 128 + c) * K_ + p0 + p] = __float2bfloat16(Y[c * 33 + p]);
    }
}

// ---------------------------------------------------------------------------
// q projection via MFMA, LDS-staged activations. grid (HW/128, B), 256 thr.
// Xs tile: 128 pos x 256 B (stride 272) staged with coalesced float4 loads
// (32 KB contiguous global run); B-frags = bank-floor b128 reads.
// ---------------------------------------------------------------------------
__global__ __launch_bounds__(256, 2) void qproj_kernel(
    const bf16* __restrict__ qt,
    const __bf16* __restrict__ W1, const float* __restrict__ sh1,
    const __bf16* __restrict__ W2, const float* __restrict__ sh2,
    bf16* __restrict__ qbuf)
{
    __shared__ __align__(16) char Xs[128 * XSTRIDE];
    __shared__ __align__(16) __bf16 Ys[128 * 136];
    const int t = threadIdx.x, w = t >> 6, lane = t & 63;
    const int pl = lane & 15, quad = lane >> 4;
    const int n0 = blockIdx.x * 128, b = blockIdx.y;
    const int ob = 32 * w;

    // ---- stage qt tile (contiguous 32 KB) into Xs
    {
        const char* qg = (const char*)(qt + ((size_t)b * HW_ + n0) * 128) + t * 16;
        char* xl = Xs + (t >> 4) * XSTRIDE + (t & 15) * 16;
#pragma unroll
        for (int i = 0; i < 8; ++i)
            *(float4*)(xl + i * 16 * XSTRIDE) = *(const float4*)(qg + i * 4096);
    }

    b8v W1f[2][4], W2f[2][4];
#pragma unroll
    for (int mt = 0; mt < 2; ++mt)
#pragma unroll
        for (int s = 0; s < 4; ++s) {
            W1f[mt][s] = ldb8(W1 + (ob + mt * 16 + pl) * 128 + s * 32 + quad * 8);
            W2f[mt][s] = ldb8(W2 + (ob + mt * 16 + pl) * 128 + s * 32 + quad * 8);
        }
    __syncthreads();

    f4v acc[2][8];
#pragma unroll
    for (int mt = 0; mt < 2; ++mt)
#pragma unroll
        for (int nt = 0; nt < 8; ++nt) acc[mt][nt] = (f4v){0.f, 0.f, 0.f, 0.f};

#pragma unroll
    for (int s = 0; s < 4; ++s) {
        b8v Bf[8];
#pragma unroll
        for (int nt = 0; nt < 8; ++nt)
            Bf[nt] = ldb8(Xs + (nt * 16 + pl) * XSTRIDE + s * 64 + quad * 16);
#pragma unroll
        for (int mt = 0; mt < 2; ++mt)
#pragma unroll
            for (int nt = 0; nt < 8; ++nt)
                acc[mt][nt] = __builtin_amdgcn_mfma_f32_16x16x32_bf16(W1f[mt][s], Bf[nt], acc[mt][nt], 0, 0, 0);
    }

    // epilogue 1: shift + relu -> Ys[p][o]
#pragma unroll
    for (int mt = 0; mt < 2; ++mt) {
        const float4 s4 = *(const float4*)(sh1 + ob + mt * 16 + quad * 4);
        const float shf[4] = {s4.x, s4.y, s4.z, s4.w};
#pragma unroll
        for (int nt = 0; nt < 8; ++nt) {
            b4v y;
#pragma unroll
            for (int r = 0; r < 4; ++r) y[r] = (__bf16)fmaxf(acc[mt][nt][r] + shf[r], 0.f);
            *(b4v*)&Ys[(nt * 16 + pl) * 136 + ob + mt * 16 + quad * 4] = y;
        }
    }
    __syncthreads();

    f4v acc2[2][8];
#pragma unroll
    for (int mt = 0; mt < 2; ++mt)
#pragma unroll
        for (int nt = 0; nt < 8; ++nt) acc2[mt][nt] = (f4v){0.f, 0.f, 0.f, 0.f};

#pragma unroll
    for (int s = 0; s < 4; ++s) {
        b8v Bf[8];
#pragma unroll
        for (int nt = 0; nt < 8; ++nt)
            Bf[nt] = *(const b8v*)&Ys[(nt * 16 + pl) * 136 + s * 32 + quad * 8];
#pragma unroll
        for (int mt = 0; mt < 2; ++mt)
#pragma unroll
            for (int nt = 0; nt < 8; ++nt)
                acc2[mt][nt] = __builtin_amdgcn_mfma_f32_16x16x32_bf16(W2f[mt][s], Bf[nt], acc2[mt][nt], 0, 0, 0);
    }

    bf16* qb = qbuf + ((size_t)b * HW_ + n0) * 128;
#pragma unroll
    for (int mt = 0; mt < 2; ++mt) {
        const float4 s4 = *(const float4*)(sh2 + ob + mt * 16 + quad * 4);
        const float shf[4] = {s4.x, s4.y, s4.z, s4.w};
#pragma unroll
        for (int nt = 0; nt < 8; ++nt) {
            b4v y;
#pragma unroll
            for (int r = 0; r < 4; ++r) y[r] = (__bf16)fmaxf(acc2[mt][nt][r] + shf[r], 0.f);
            *(b4v*)(qb + (size_t)(nt * 16 + pl) * 128 + ob + mt * 16 + quad * 4) = y;
        }
    }
}

// ---------------------------------------------------------------------------
// Kernel 3: flash attention (unchanged from R6). grid (HW/64, B), 256 thr.
// ---------------------------------------------------------------------------
#define KSTRIDE 272
#define VSTRIDE 136
__global__ __launch_bounds__(256, 2) void attn_kernel(
    const bf16* __restrict__ qbuf, const bf16* __restrict__ kbuf, const bf16* __restrict__ vbuf,
    const int* __restrict__ mask, bf16* __restrict__ ctxbuf)
{
    __shared__ __align__(16) float bias[K_];
    __shared__ __align__(16) char ktile[64 * KSTRIDE];
    __shared__ __align__(16) char vtile[128 * VSTRIDE];

    const int t    = threadIdx.x;
    const int w    = t >> 6;
    const int lane = t & 63;
    const int m    = lane & 15;
    const int quad = lane >> 4;
    const int q0   = blockIdx.x * 64;
    const int b    = blockIdx.y;

    for (int i = t; i < K_; i += 256)
        bias[i] = (mask[b * K_ + i] != 0) ? 0.f : NEG_;

    b8v qf[4];
    {
        const bf16* qrow = qbuf + ((size_t)b * HW_ + q0 + w * 16 + m) * 128;
#pragma unroll
        for (int s = 0; s < 4; ++s) qf[s] = ldb8(qrow + s * 32 + quad * 8);
    }

    const bf16* kpt = kbuf + (size_t)b * K_ * 128;
    const bf16* vpt = vbuf + (size_t)b * 128 * K_;

    const char* kg = (const char*)kpt + t * 16;
    const char* vg = (const char*)(vpt + (size_t)(t >> 3) * K_) + (t & 7) * 16;
    char* kl = ktile + (t >> 4) * KSTRIDE + (t & 15) * 16;
    char* vl = vtile + (t >> 3) * VSTRIDE + (t & 7) * 16;

    float4 k_r0 = *(const float4*)(kg);
    float4 k_r1 = *(const float4*)(kg + 4096);
    float4 k_r2 = *(const float4*)(kg + 8192);
    float4 k_r3 = *(const float4*)(kg + 12288);
    float4 v_r0 = *(const float4*)(vg);
    float4 v_r1 = *(const float4*)(vg + 65536);
    float4 v_r2 = *(const float4*)(vg + 131072);
    float4 v_r3 = *(const float4*)(vg + 196608);

    f4v acc[8];
#pragma unroll
    for (int i = 0; i < 8; ++i) acc[i] = (f4v){0.f, 0.f, 0.f, 0.f};
    float mrun = -3.0e38f, lrun = 0.f;

    for (int chunk = 0; chunk < 16; ++chunk) {
        const int k0 = chunk * 64;

        *(float4*)(kl)                = k_r0;
        *(float4*)(kl + 16 * KSTRIDE) = k_r1;
        *(float4*)(kl + 32 * KSTRIDE) = k_r2;
        *(float4*)(kl + 48 * KSTRIDE) = k_r3;
        *(float4*)(vl)                = v_r0;
        *(float4*)(vl + 32 * VSTRIDE) = v_r1;
        *(float4*)(vl + 64 * VSTRIDE) = v_r2;
        *(float4*)(vl + 96 * VSTRIDE) = v_r3;
        __syncthreads();

        if (chunk < 15) {
            const char* kgn = kg + (chunk + 1) * 16384;
            const char* vgn = vg + (chunk + 1) * 128;
            k_r0 = *(const float4*)(kgn);
            k_r1 = *(const float4*)(kgn + 4096);
            k_r2 = *(const float4*)(kgn + 8192);
            k_r3 = *(const float4*)(kgn + 12288);
            v_r0 = *(const float4*)(vgn);
            v_r1 = *(const float4*)(vgn + 65536);
            v_r2 = *(const float4*)(vgn + 131072);
            v_r3 = *(const float4*)(vgn + 196608);
        }

        f4v sv[4];
#pragma unroll
        for (int kt = 0; kt < 4; ++kt) {
            f4v a = (f4v){0.f, 0.f, 0.f, 0.f};
            const char* krow = ktile + (kt * 16 + m) * KSTRIDE + quad * 16;
#pragma unroll
            for (int s = 0; s < 4; ++s)
                a = __builtin_amdgcn_mfma_f32_16x16x32_bf16(ldb8(krow + s * 64), qf[s], a, 0, 0, 0);
            const float4 b4 = *(const float4*)&bias[k0 + kt * 16 + quad * 4];
            const float bb4[4] = {b4.x, b4.y, b4.z, b4.w};
#pragma unroll
            for (int r = 0; r < 4; ++r) sv[kt][r] = a[r] * SCALE_ + bb4[r];
        }

        float mloc = sv[0][0];
#pragma unroll
        for (int kt = 0; kt < 4; ++kt)
#pragma unroll
            for (int r = 0; r < 4; ++r) mloc = fmaxf(mloc, sv[kt][r]);
        mloc = fmaxf(mloc, __shfl_xor(mloc, 16, 64));
        mloc = fmaxf(mloc, __shfl_xor(mloc, 32, 64));
        const float mn = fmaxf(mrun, mloc);
        const float alpha = __expf(mrun - mn);
        mrun = mn;

        b4v pk[4];
        float rs = 0.f;
#pragma unroll
        for (int kt = 0; kt < 4; ++kt)
#pragma unroll
            for (int r = 0; r < 4; ++r) {
                const float p = __expf(sv[kt][r] - mn);
                rs += p;
                pk[kt][r] = (__bf16)p;
            }
        rs += __shfl_xor(rs, 16, 64);
        rs += __shfl_xor(rs, 32, 64);
        lrun = lrun * alpha + rs;

        float alr[4];
#pragma unroll
        for (int r = 0; r < 4; ++r) alr[r] = __shfl(alpha, quad * 4 + r, 64);
#pragma unroll
        for (int ct = 0; ct < 8; ++ct)
#pragma unroll
            for (int r = 0; r < 4; ++r) acc[ct][r] *= alr[r];

        const b8v A0 = __builtin_shufflevector(pk[0], pk[1], 0, 1, 2, 3, 4, 5, 6, 7);
        const b8v A1 = __builtin_shufflevector(pk[2], pk[3], 0, 1, 2, 3, 4, 5, 6, 7);
#pragma unroll
        for (int ct = 0; ct < 8; ++ct) {
            const char* vrow = vtile + (ct * 16 + m) * VSTRIDE + quad * 8;
            const b8v B0 = __builtin_shufflevector(ldb4(vrow),      ldb4(vrow + 32), 0, 1, 2, 3, 4, 5, 6, 7);
            const b8v B1 = __builtin_shufflevector(ldb4(vrow + 64), ldb4(vrow + 96), 0, 1, 2, 3, 4, 5, 6, 7);
            acc[ct] = __builtin_amdgcn_mfma_f32_16x16x32_bf16(A0, B0, acc[ct], 0, 0, 0);
            acc[ct] = __builtin_amdgcn_mfma_f32_16x16x32_bf16(A1, B1, acc[ct], 0, 0, 0);
        }
        __syncthreads();
    }

    float inv[4];
#pragma unroll
    for (int r = 0; r < 4; ++r) inv[r] = 1.f / __shfl(lrun, quad * 4 + r, 64);
    bf16* crow = ctxbuf + ((size_t)b * HW_ + q0 + w * 16) * 128;
#pragma unroll
    for (int ct = 0; ct < 8; ++ct)
#pragma unroll
        for (int r = 0; r < 4; ++r)
            crow[(size_t)(quad * 4 + r) * 128 + ct * 16 + m] = __float2bfloat16(acc[ct][r] * inv[r]);
}

// ---------------------------------------------------------------------------
// Final: ctx2 = relu(Wo'@ctx + bo); out = relu(Wb'@[ctx2;qt] + bb) via MFMA.
// Xs staged twice: ctx for layer 1, then qt for layer 2 (loads issued early
// to overlap layer-1 compute). grid (HW/128, B), 256 threads.
// ---------------------------------------------------------------------------
__global__ __launch_bounds__(256, 2) void final_kernel(
    const bf16* __restrict__ ctx, const bf16* __restrict__ qt,
    const __bf16* __restrict__ Wop, const float* __restrict__ bo,
    const __bf16* __restrict__ Wbp, const float* __restrict__ bb,
    float* __restrict__ out)
{
    __shared__ __align__(16) char Xs[128 * XSTRIDE];
    __shared__ __align__(16) __bf16 Ys[128 * 136];
    const int t = threadIdx.x, w = t >> 6, lane = t & 63;
    const int pl = lane & 15, quad = lane >> 4;
    const int n0 = blockIdx.x * 128, b = blockIdx.y;
    const int ob = 32 * w;

    char* xl = Xs + (t >> 4) * XSTRIDE + (t & 15) * 16;

    // ---- stage ctx tile (contiguous 32 KB) into Xs
    {
        const char* cg = (const char*)(ctx + ((size_t)b * HW_ + n0) * 128) + t * 16;
#pragma unroll
        for (int i = 0; i < 8; ++i)
            *(float4*)(xl + i * 16 * XSTRIDE) = *(const float4*)(cg + i * 4096);
    }

    b8v Wof[2][4];
#pragma unroll
    for (int mt = 0; mt < 2; ++mt)
#pragma unroll
        for (int s = 0; s < 4; ++s)
            Wof[mt][s] = ldb8(Wop + (ob + mt * 16 + pl) * 128 + s * 32 + quad * 8);
    __syncthreads();

    // ---- issue qt staging loads now; consumed after layer 1
    const char* qg = (const char*)(qt + ((size_t)b * HW_ + n0) * 128) + t * 16;
    float4 q_s0 = *(const float4*)(qg);
    float4 q_s1 = *(const float4*)(qg + 4096);
    float4 q_s2 = *(const float4*)(qg + 8192);
    float4 q_s3 = *(const float4*)(qg + 12288);
    float4 q_s4 = *(const float4*)(qg + 16384);
    float4 q_s5 = *(const float4*)(qg + 20480);
    float4 q_s6 = *(const float4*)(qg + 24576);
    float4 q_s7 = *(const float4*)(qg + 28672);

    // ---- layer 1: ctx2 = relu(Wo' @ ctx + bo)
    f4v acc1[2][8];
#pragma unroll
    for (int mt = 0; mt < 2; ++mt)
#pragma unroll
        for (int nt = 0; nt < 8; ++nt) acc1[mt][nt] = (f4v){0.f, 0.f, 0.f, 0.f};

#pragma unroll
    for (int s = 0; s < 4; ++s) {
        b8v Bf[8];
#pragma unroll
        for (int nt = 0; nt < 8; ++nt)
            Bf[nt] = ldb8(Xs + (nt * 16 + pl) * XSTRIDE + s * 64 + quad * 16);
#pragma unroll
        for (int mt = 0; mt < 2; ++mt)
#pragma unroll
            for (int nt = 0; nt < 8; ++nt)
                acc1[mt][nt] = __builtin_amdgcn_mfma_f32_16x16x32_bf16(Wof[mt][s], Bf[nt], acc1[mt][nt], 0, 0, 0);
    }

#pragma unroll
    for (int mt = 0; mt < 2; ++mt) {
        const float4 s4 = *(const float4*)(bo + ob + mt * 16 + quad * 4);
        const float shf[4] = {s4.x, s4.y, s4.z, s4.w};
#pragma unroll
        for (int nt = 0; nt < 8; ++nt) {
            b4v y;
#pragma unroll
            for (int r = 0; r < 4; ++r) y[r] = (__bf16)fmaxf(acc1[mt][nt][r] + shf[r], 0.f);
            *(b4v*)&Ys[(nt * 16 + pl) * 136 + ob + mt * 16 + quad * 4] = y;
        }
    }
    __syncthreads();    // Xs reads done, Ys visible

    // ---- restage Xs with qt tile
    *(float4*)(xl)                 = q_s0;
    *(float4*)(xl + 16 * XSTRIDE)  = q_s1;
    *(float4*)(xl + 32 * XSTRIDE)  = q_s2;
    *(float4*)(xl + 48 * XSTRIDE)  = q_s3;
    *(float4*)(xl + 64 * XSTRIDE)  = q_s4;
    *(float4*)(xl + 80 * XSTRIDE)  = q_s5;
    *(float4*)(xl + 96 * XSTRIDE)  = q_s6;
    *(float4*)(xl + 112 * XSTRIDE) = q_s7;
    __syncthreads();

    // ---- layer 2: M=256, K=256 (Ys for ks<4, Xs(qt) for ks>=4)
    f4v acc2[4][8];
#pragma unroll
    for (int mt = 0; mt < 4; ++mt)
#pragma unroll
        for (int nt = 0; nt < 8; ++nt) acc2[mt][nt] = (f4v){0.f, 0.f, 0.f, 0.f};

#pragma unroll
    for (int ks = 0; ks < 8; ++ks) {
        b8v Af[4];
#pragma unroll
        for (int mt = 0; mt < 4; ++mt)
            Af[mt] = ldb8(Wbp + (64 * w + mt * 16 + pl) * 256 + ks * 32 + quad * 8);
        b8v Bf[8];
        if (ks < 4) {
#pragma unroll
            for (int nt = 0; nt < 8; ++nt)
                Bf[nt] = *(const b8v*)&Ys[(nt * 16 + pl) * 136 + ks * 32 + quad * 8];
        } else {
#pragma unroll
            for (int nt = 0; nt < 8; ++nt)
                Bf[nt] = ldb8(Xs + (nt * 16 + pl) * XSTRIDE + (ks - 4) * 64 + quad * 16);
        }
#pragma unroll
        for (int mt = 0; mt < 4; ++mt)
#pragma unroll
            for (int nt = 0; nt < 8; ++nt)
                acc2[mt][nt] = __builtin_amdgcn_mfma_f32_16x16x32_bf16(Af[mt], Bf[nt], acc2[mt][nt], 0, 0, 0);
    }

#pragma unroll
    for (int mt = 0; mt < 4; ++mt) {
        const float4 s4 = *(const float4*)(bb + 64 * w + mt * 16 + quad * 4);
        const float shf[4] = {s4.x, s4.y, s4.z, s4.w};
#pragma unroll
        for (int nt = 0; nt < 8; ++nt)
#pragma unroll
            for (int r = 0; r < 4; ++r)
                out[(size_t)(b * 256 + 64 * w + mt * 16 + quad * 4 + r) * HW_ + n0 + nt * 16 + pl]
                    = fmaxf(acc2[mt][nt][r] + shf[r], 0.f);
    }
}

// ---------------------------------------------------------------------------
extern "C" void kernel_launch(void* const* d_in, const int* in_sizes, int n_in,
                              void* d_out, int out_size, void* d_ws, size_t ws_size,
                              hipStream_t stream)
{
    const float* query = (const float*)d_in[0];
    const float* key   = (const float*)d_in[1];
    const float* val   = (const float*)d_in[2];
    const int*   mask  = (const int*)  d_in[3];
    const float* Wq1 = (const float*)d_in[4];  const float* sq1 = (const float*)d_in[5];  const float* bq1 = (const float*)d_in[6];
    const float* Wq2 = (const float*)d_in[7];  const float* sq2 = (const float*)d_in[8];  const float* bq2 = (const float*)d_in[9];
    const float* Wk1 = (const float*)d_in[10]; const float* sk1 = (const float*)d_in[11]; const float* bk1 = (const float*)d_in[12];
    const float* Wk2 = (const float*)d_in[13]; const float* sk2 = (const float*)d_in[14]; const float* bk2 = (const float*)d_in[15];
    const float* Wv  = (const float*)d_in[16]; const float* sv  = (const float*)d_in[17]; const float* bv  = (const float*)d_in[18];
    const float* Wo  = (const float*)d_in[19]; const float* so  = (const float*)d_in[20]; const float* bo  = (const float*)d_in[21];
    const float* Wb  = (const float*)d_in[22]; const float* sb  = (const float*)d_in[23]; const float* bb  = (const float*)d_in[24];

    char* ws = (char*)d_ws;
    bf16*   kbuf = (bf16*)(ws);                        // [B][K][C] bf16  : 1 MB
    bf16*   vbuf = (bf16*)(ws + (1u << 20));           // [B][C][K] bf16  : 1 MB
    bf16*   qbuf = (bf16*)(ws + (2u << 20));           // [B][HW][C] bf16 : 16 MB
    bf16*   ctxb = (bf16*)(ws + (18u << 20));          // [B][HW][C] bf16 : 16 MB
    bf16*   qt   = (bf16*)(ws + (34u << 20));          // [B][HW][C] bf16 : 16 MB
    __bf16* Wq1p = (__bf16*)(ws + (50u << 20));                  // 32 KB
    __bf16* Wq2p = (__bf16*)(ws + (50u << 20) + (32u << 10));    // 32 KB
    __bf16* Wop  = (__bf16*)(ws + (50u << 20) + (64u << 10));    // 32 KB
    __bf16* Wbp  = (__bf16*)(ws + (50u << 20) + (96u << 10));    // 128 KB
    float* outp = (float*)d_out;

    wprep_kernel<<<448, 256, 0, stream>>>(Wq1, sq1, Wq2, sq2, Wo, so, Wb, sb,
                                          Wq1p, Wq2p, Wop, Wbp);
    tq_kernel<<<dim3(HW_ / 64, B_), 256, 0, stream>>>(query, qt);
    kv_proj_kernel<<<dim3(K_ / 32, B_), 256, 0, stream>>>(
        key, val, Wk1, sk1, bk1, Wk2, sk2, bk2, Wv, sv, bv, kbuf, vbuf);
    qproj_kernel<<<dim3(HW_ / 128, B_), 256, 0, stream>>>(
        qt, Wq1p, bq1, Wq2p, bq2, qbuf);
    attn_kernel<<<dim3(HW_ / 64, B_), 256, 0, stream>>>(
        qbuf, kbuf, vbuf, mask, ctxb);
    final_kernel<<<dim3(HW_ / 128, B_), 256, 0, stream>>>(
        ctxb, qt, Wop, bo, Wbp, bb, outp);
}